// Round 2
// baseline (588.374 us; speedup 1.0000x reference)
//
#include <hip/hip_runtime.h>

typedef __attribute__((ext_vector_type(8))) short s16x8;
typedef __attribute__((ext_vector_type(4))) float f32x4;
typedef __attribute__((ext_vector_type(4))) unsigned short u16x4;

#define T_  2048
#define C_  1024
#define D_  64

__device__ __forceinline__ unsigned short f2bf(float f){
  union { float fv; unsigned int u; } v; v.fv = f;
  unsigned int r = v.u + 0x7FFFu + ((v.u >> 16) & 1u);
  return (unsigned short)(r >> 16);
}

__device__ __forceinline__ void gload_lds16(const void* g, void* l){
  __builtin_amdgcn_global_load_lds(
      (const __attribute__((address_space(1))) unsigned int*)g,
      (__attribute__((address_space(3))) unsigned int*)l, 16, 0, 0);
}

// ---------------- fp32 -> bf16 convert, 8 elems/thread ----------------
__global__ __launch_bounds__(256) void cvt_kernel(const float* __restrict__ src,
                                                  unsigned short* __restrict__ dst){
  size_t i = ((size_t)blockIdx.x * 256u + threadIdx.x) * 8u;
  f32x4 a = *(const f32x4*)(src + i);
  f32x4 b = *(const f32x4*)(src + i + 4);
  s16x8 o;
  #pragma unroll
  for (int j = 0; j < 4; ++j){ o[j] = (short)f2bf(a[j]); o[4+j] = (short)f2bf(b[j]); }
  *(s16x8*)(dst + i) = o;
}

// ---------------- GEMM: C[m,n] = sum_k A[m,k]*Bw[n,k] + bias[n] ----------------
template<int MODE>
__global__ __launch_bounds__(256) void gemm_bt(
    const unsigned short* __restrict__ A, const unsigned short* __restrict__ Bw,
    const float* __restrict__ bias, int M, int N, int K,
    unsigned short* __restrict__ q_ws, unsigned short* __restrict__ k_ws,
    unsigned short* __restrict__ vT_ws, float* __restrict__ out)
{
  __shared__ unsigned short As[128*32];
  __shared__ unsigned short Bs[128*32];
  const int tid = threadIdx.x;
  const int lane = tid & 63, wid = tid >> 6;
  const int g = lane >> 4, lr = lane & 15;
  const int m0 = blockIdx.y * 128, n0 = blockIdx.x * 128;
  const int wr = wid >> 1, wc = wid & 1;

  f32x4 acc[4][4];
  #pragma unroll
  for (int i = 0; i < 4; ++i)
    #pragma unroll
    for (int j = 0; j < 4; ++j) acc[i][j] = (f32x4){0.f,0.f,0.f,0.f};

  const int nk = K >> 5;
  for (int kt = 0; kt < nk; ++kt){
    const int k0 = kt << 5;
    #pragma unroll
    for (int j = 0; j < 2; ++j){
      const int c = wid*128 + j*64 + lane;
      const int row = c >> 2, kc = c & 3;
      gload_lds16((const char*)A  + (((size_t)(m0+row))*K + k0)*2 + kc*16,
                  (char*)As + (size_t)(wid*128 + j*64)*16);
      gload_lds16((const char*)Bw + (((size_t)(n0+row))*K + k0)*2 + kc*16,
                  (char*)Bs + (size_t)(wid*128 + j*64)*16);
    }
    __syncthreads();
    s16x8 af[4], bf[4];
    #pragma unroll
    for (int i = 0; i < 4; ++i)
      af[i] = *(const s16x8*)&As[(wr*64 + i*16 + lr)*32 + g*8];
    #pragma unroll
    for (int j = 0; j < 4; ++j)
      bf[j] = *(const s16x8*)&Bs[(wc*64 + j*16 + lr)*32 + g*8];
    #pragma unroll
    for (int i = 0; i < 4; ++i)
      #pragma unroll
      for (int j = 0; j < 4; ++j)
        acc[i][j] = __builtin_amdgcn_mfma_f32_16x16x32_bf16(af[i], bf[j], acc[i][j], 0, 0, 0);
    __syncthreads();
  }

  #pragma unroll
  for (int i = 0; i < 4; ++i){
    #pragma unroll
    for (int j = 0; j < 4; ++j){
      const int n = n0 + wc*64 + j*16 + lr;
      const float bv = bias[n];
      #pragma unroll
      for (int r = 0; r < 4; ++r){
        const int m = m0 + wr*64 + i*16 + g*4 + r;
        const float val = acc[i][j][r] + bv;
        if (MODE == 0){
          const int which = n >> 10;
          const int cc = n & 1023;
          const int h = cc >> 6, d = cc & 63;
          const int bq = m >> 11, t = m & 2047;
          const int bh = bq*16 + h;
          if (which == 0)      q_ws[((size_t)bh*T_ + t)*D_ + d] = f2bf(val * 0.015625f);
          else if (which == 1) k_ws[((size_t)bh*T_ + t)*D_ + d] = f2bf(val);
          else                 vT_ws[((size_t)bh*D_ + d)*T_ + t] = f2bf(val);
        } else {
          out[(size_t)m*N + n] = val;
        }
      }
    }
  }
}

// ---------------- flash attention, swapped-operand form ----------------
// Wave handles 16 queries. S^T = mfma(K,Q): lane holds 8 scores for query
// q = lane&15 -> per-query softmax is in-lane + 2 shuffles. y^T = mfma(V^T,P):
// output col is also q = lane&15 -> corr & 1/l apply per-lane, no shuffling.
__global__ __launch_bounds__(256) void attn_kernel(
    const unsigned short* __restrict__ q_ws, const unsigned short* __restrict__ k_ws,
    const unsigned short* __restrict__ vT_ws, unsigned short* __restrict__ y_ws)
{
  __shared__ __align__(16) unsigned short P_lds[4][16*40];   // 40-short row stride: 2-way banks (free)
  const int tid = threadIdx.x;
  const int lane = tid & 63, wid = tid >> 6;
  const int g = lane >> 4, lr = lane & 15;
  const int qt = (int)gridDim.x - 1 - (int)blockIdx.x;       // heavy q-tiles dispatch first
  const int bh = blockIdx.y;
  const int qw0 = qt*64 + wid*16;

  const unsigned short* Qb = q_ws  + (size_t)bh*T_*D_;
  const unsigned short* Kb = k_ws  + (size_t)bh*T_*D_;
  const unsigned short* Vb = vT_ws + (size_t)bh*D_*T_;
  unsigned short* Pw = &P_lds[wid][0];

  // Q as B-operand fragments: lane reads Q[qw0+lr][d], d = g*8.. / 32+g*8..
  const s16x8 bq0 = *(const s16x8*)&Qb[(size_t)(qw0+lr)*D_ + g*8];
  const s16x8 bq1 = *(const s16x8*)&Qb[(size_t)(qw0+lr)*D_ + 32 + g*8];

  f32x4 yacc[4];
  #pragma unroll
  for (int dt = 0; dt < 4; ++dt) yacc[dt] = (f32x4){0.f,0.f,0.f,0.f};
  float mrun = -1e30f, lrun = 0.f;                           // per query q = lane&15
  const int qrow = qw0 + lr;
  const int ntile = ((qw0 + 15) >> 5) + 1;

  auto loadKV = [&](int t, s16x8& a00, s16x8& a01, s16x8& a10, s16x8& a11, s16x8 av[4]){
    const int kt0 = t << 5;
    a00 = *(const s16x8*)&Kb[(size_t)(kt0 + lr)*D_ + g*8];
    a01 = *(const s16x8*)&Kb[(size_t)(kt0 + lr)*D_ + 32 + g*8];
    a10 = *(const s16x8*)&Kb[(size_t)(kt0 + 16 + lr)*D_ + g*8];
    a11 = *(const s16x8*)&Kb[(size_t)(kt0 + 16 + lr)*D_ + 32 + g*8];
    #pragma unroll
    for (int dt = 0; dt < 4; ++dt)
      av[dt] = *(const s16x8*)&Vb[(size_t)(dt*16 + lr)*T_ + kt0 + g*8];
  };

  s16x8 k00, k01, k10, k11, av[4];
  loadKV(0, k00, k01, k10, k11, av);

  for (int t = 0; t < ntile; ++t){
    const int kt0 = t << 5;
    // register double-buffer: issue next tile's K/V loads before compute
    s16x8 n00, n01, n10, n11, nav[4];
    const int tn = (t + 1 < ntile) ? t + 1 : t;
    loadKV(tn, n00, n01, n10, n11, nav);

    f32x4 s0 = (f32x4){0.f,0.f,0.f,0.f}, s1 = (f32x4){0.f,0.f,0.f,0.f};
    s0 = __builtin_amdgcn_mfma_f32_16x16x32_bf16(k00, bq0, s0, 0, 0, 0);
    s0 = __builtin_amdgcn_mfma_f32_16x16x32_bf16(k01, bq1, s0, 0, 0, 0);
    s1 = __builtin_amdgcn_mfma_f32_16x16x32_bf16(k10, bq0, s1, 0, 0, 0);
    s1 = __builtin_amdgcn_mfma_f32_16x16x32_bf16(k11, bq1, s1, 0, 0, 0);

    // lane holds S[q=lr][k=kt0+g*4+r] (s0) and [k=kt0+16+g*4+r] (s1)
    float mx = -1e30f;
    #pragma unroll
    for (int r = 0; r < 4; ++r){
      const float v0 = (kt0 + g*4 + r      <= qrow) ? s0[r] : -1e30f;
      const float v1 = (kt0 + 16 + g*4 + r <= qrow) ? s1[r] : -1e30f;
      s0[r] = v0; s1[r] = v1;
      mx = fmaxf(mx, fmaxf(v0, v1));
    }
    mx = fmaxf(mx, __shfl_xor(mx, 16, 64));
    mx = fmaxf(mx, __shfl_xor(mx, 32, 64));
    const float mnew = fmaxf(mrun, mx);
    const float corr = __expf(mrun - mnew);
    mrun = mnew;

    float rs = 0.f;
    u16x4 w0, w1;
    #pragma unroll
    for (int r = 0; r < 4; ++r){
      const float e0 = __expf(s0[r] - mnew);
      const float e1 = __expf(s1[r] - mnew);
      rs += e0 + e1;
      w0[r] = f2bf(e0); w1[r] = f2bf(e1);
    }
    rs += __shfl_xor(rs, 16, 64);
    rs += __shfl_xor(rs, 32, 64);
    lrun = lrun * corr + rs;

    // re-fragment P via tiny per-wave LDS: 2x ds_write_b64 + 1x ds_read_b128
    *(u16x4*)&Pw[lr*40 + g*4]      = w0;
    *(u16x4*)&Pw[lr*40 + 16 + g*4] = w1;
    asm volatile("" ::: "memory");
    const s16x8 pa = *(const s16x8*)&Pw[lr*40 + g*8];

    #pragma unroll
    for (int dt = 0; dt < 4; ++dt){
      #pragma unroll
      for (int r = 0; r < 4; ++r) yacc[dt][r] *= corr;
      yacc[dt] = __builtin_amdgcn_mfma_f32_16x16x32_bf16(av[dt], pa, yacc[dt], 0, 0, 0);
    }

    k00 = n00; k01 = n01; k10 = n10; k11 = n11;
    #pragma unroll
    for (int dt = 0; dt < 4; ++dt) av[dt] = nav[dt];
  }

  // y^T layout: lane holds y[q=lr][d = dt*16 + g*4 + r]
  const int bq = bh >> 4, h = bh & 15;
  const float inv = 1.f / lrun;
  #pragma unroll
  for (int dt = 0; dt < 4; ++dt){
    u16x4 w;
    #pragma unroll
    for (int r = 0; r < 4; ++r) w[r] = f2bf(yacc[dt][r] * inv);
    *(u16x4*)&y_ws[((size_t)(bq*T_ + qw0 + lr))*C_ + h*64 + dt*16 + g*4] = w;
  }
}

extern "C" void kernel_launch(void* const* d_in, const int* in_sizes, int n_in,
                              void* d_out, int out_size, void* d_ws, size_t ws_size,
                              hipStream_t stream) {
  const float* x  = (const float*)d_in[0];
  const float* Wa = (const float*)d_in[1];
  const float* ba = (const float*)d_in[2];
  const float* Wp = (const float*)d_in[3];
  const float* bp = (const float*)d_in[4];
  float* out = (float*)d_out;

  char* ws = (char*)d_ws;
  const size_t MB = 1024u*1024u;
  unsigned short* xb  = (unsigned short*)(ws + 0);       // 16 MiB  [8192][1024] bf16
  unsigned short* wab = (unsigned short*)(ws + 16*MB);   //  6 MiB  [3072][1024]
  unsigned short* wpb = (unsigned short*)(ws + 22*MB);   //  2 MiB  [1024][1024]
  unsigned short* qws = (unsigned short*)(ws + 24*MB);   // 16 MiB  [64][2048][64]
  unsigned short* kws = (unsigned short*)(ws + 40*MB);   // 16 MiB  [64][2048][64]
  unsigned short* vT  = (unsigned short*)(ws + 56*MB);   // 16 MiB  [64][64][2048]
  unsigned short* yws = (unsigned short*)(ws + 72*MB);   // 16 MiB  [8192][1024]

  cvt_kernel<<<4096, 256, 0, stream>>>(x,  xb);
  cvt_kernel<<<1536, 256, 0, stream>>>(Wa, wab);
  cvt_kernel<<< 512, 256, 0, stream>>>(Wp, wpb);

  gemm_bt<0><<<dim3(24, 64), 256, 0, stream>>>(xb, wab, ba, 8192, 3072, 1024,
                                               qws, kws, vT, nullptr);
  attn_kernel<<<dim3(32, 64), 256, 0, stream>>>(qws, kws, vT, yws);
  gemm_bt<1><<<dim3(8, 64), 256, 0, stream>>>(yws, wpb, bp, 8192, 1024, 1024,
                                              nullptr, nullptr, nullptr, out);
}

// Round 3
// 268.621 us; speedup vs baseline: 2.1904x; 2.1904x over previous
//
#include <hip/hip_runtime.h>

typedef __attribute__((ext_vector_type(8))) short s16x8;
typedef __attribute__((ext_vector_type(4))) float f32x4;
typedef __attribute__((ext_vector_type(4))) unsigned short u16x4;

#define T_  2048
#define C_  1024
#define D_  64

__device__ __forceinline__ unsigned short f2bf(float f){
  union { float fv; unsigned int u; } v; v.fv = f;
  unsigned int r = v.u + 0x7FFFu + ((v.u >> 16) & 1u);
  return (unsigned short)(r >> 16);
}

__device__ __forceinline__ void gload_lds16(const void* g, void* l){
  __builtin_amdgcn_global_load_lds(
      (const __attribute__((address_space(1))) unsigned int*)g,
      (__attribute__((address_space(3))) unsigned int*)l, 16, 0, 0);
}

// ---------------- fp32 -> bf16 convert, 8 elems/thread ----------------
__global__ __launch_bounds__(256) void cvt_kernel(const float* __restrict__ src,
                                                  unsigned short* __restrict__ dst){
  size_t i = ((size_t)blockIdx.x * 256u + threadIdx.x) * 8u;
  f32x4 a = *(const f32x4*)(src + i);
  f32x4 b = *(const f32x4*)(src + i + 4);
  s16x8 o;
  #pragma unroll
  for (int j = 0; j < 4; ++j){ o[j] = (short)f2bf(a[j]); o[4+j] = (short)f2bf(b[j]); }
  *(s16x8*)(dst + i) = o;
}

// ---------------- GEMM: C[m,n] = sum_k A[m,k]*Bw[n,k] + bias[n] ----------------
template<int MODE>
__global__ __launch_bounds__(256) void gemm_bt(
    const unsigned short* __restrict__ A, const unsigned short* __restrict__ Bw,
    const float* __restrict__ bias, int M, int N, int K,
    unsigned short* __restrict__ q_ws, unsigned short* __restrict__ k_ws,
    unsigned short* __restrict__ vT_ws, float* __restrict__ out)
{
  __shared__ unsigned short As[128*32];
  __shared__ unsigned short Bs[128*32];
  const int tid = threadIdx.x;
  const int lane = tid & 63, wid = tid >> 6;
  const int g = lane >> 4, lr = lane & 15;
  const int m0 = blockIdx.y * 128, n0 = blockIdx.x * 128;
  const int wr = wid >> 1, wc = wid & 1;

  f32x4 acc[4][4];
  #pragma unroll
  for (int i = 0; i < 4; ++i)
    #pragma unroll
    for (int j = 0; j < 4; ++j) acc[i][j] = (f32x4){0.f,0.f,0.f,0.f};

  const int nk = K >> 5;
  for (int kt = 0; kt < nk; ++kt){
    const int k0 = kt << 5;
    #pragma unroll
    for (int j = 0; j < 2; ++j){
      const int c = wid*128 + j*64 + lane;
      const int row = c >> 2, kc = c & 3;
      gload_lds16((const char*)A  + (((size_t)(m0+row))*K + k0)*2 + kc*16,
                  (char*)As + (size_t)(wid*128 + j*64)*16);
      gload_lds16((const char*)Bw + (((size_t)(n0+row))*K + k0)*2 + kc*16,
                  (char*)Bs + (size_t)(wid*128 + j*64)*16);
    }
    __syncthreads();
    s16x8 af[4], bf[4];
    #pragma unroll
    for (int i = 0; i < 4; ++i)
      af[i] = *(const s16x8*)&As[(wr*64 + i*16 + lr)*32 + g*8];
    #pragma unroll
    for (int j = 0; j < 4; ++j)
      bf[j] = *(const s16x8*)&Bs[(wc*64 + j*16 + lr)*32 + g*8];
    #pragma unroll
    for (int i = 0; i < 4; ++i)
      #pragma unroll
      for (int j = 0; j < 4; ++j)
        acc[i][j] = __builtin_amdgcn_mfma_f32_16x16x32_bf16(af[i], bf[j], acc[i][j], 0, 0, 0);
    __syncthreads();
  }

  #pragma unroll
  for (int i = 0; i < 4; ++i){
    #pragma unroll
    for (int j = 0; j < 4; ++j){
      const int n = n0 + wc*64 + j*16 + lr;
      const float bv = bias[n];
      #pragma unroll
      for (int r = 0; r < 4; ++r){
        const int m = m0 + wr*64 + i*16 + g*4 + r;
        const float val = acc[i][j][r] + bv;
        if (MODE == 0){
          const int which = n >> 10;
          const int cc = n & 1023;
          const int h = cc >> 6, d = cc & 63;
          const int bq = m >> 11, t = m & 2047;
          const int bh = bq*16 + h;
          if (which == 0)      q_ws[((size_t)bh*T_ + t)*D_ + d] = f2bf(val * 0.015625f);
          else if (which == 1) k_ws[((size_t)bh*T_ + t)*D_ + d] = f2bf(val);
          else                 vT_ws[((size_t)bh*D_ + d)*T_ + t] = f2bf(val);
        } else {
          out[(size_t)m*N + n] = val;
        }
      }
    }
  }
}

// ---------------- flash attention v3: block-level LDS staging, 64-key tiles ----------------
// Block = 4 waves = 64 queries (16/wave), all waves share staged K/V^T tiles.
// S^T = mfma(K,Q) -> lane owns query q=lane&15 (in-lane softmax).
// y^T = mfma(V^T,P) -> same lane mapping, corr/1/l per-lane.
// All 128B-stride LDS rows XOR-swizzled: byte ^= ((row&7)<<4); global source
// pre-swizzled so global_load_lds' linear dest ends up swizzled (rule #21).
__global__ __launch_bounds__(256, 4) void attn_kernel(
    const unsigned short* __restrict__ q_ws, const unsigned short* __restrict__ k_ws,
    const unsigned short* __restrict__ vT_ws, unsigned short* __restrict__ y_ws)
{
  __shared__ __align__(16) unsigned short Ks[2][64*64];   // [key][d]   8KB x2
  __shared__ __align__(16) unsigned short Vs[2][64*64];   // [d][key]   8KB x2
  __shared__ __align__(16) unsigned short Ps[4][16*64];   // per-wave [q][k] 2KB

  const int tid = threadIdx.x;
  const int lane = tid & 63, wid = tid >> 6;
  const int g = lane >> 4, lr = lane & 15;
  const int qt = (int)gridDim.x - 1 - (int)blockIdx.x;    // heavy q-tiles first
  const int bh = blockIdx.y;
  const int q0 = qt*64;
  const int qw0 = q0 + wid*16;
  const int qrow = qw0 + lr;
  const int swz = (lr & 7) << 4;                           // per-lane row-XOR (all our rows have row&7 == lr&7)

  const unsigned short* Qb = q_ws  + (size_t)bh*T_*D_;
  const unsigned short* Kb = k_ws  + (size_t)bh*T_*D_;
  const unsigned short* Vb = vT_ws + (size_t)bh*D_*T_;
  unsigned short* Pw = &Ps[wid][0];

  // stage one 64-key tile: K rows + V^T rows, inverse-swizzled source, linear LDS dest
  auto stage = [&](int t, int buf){
    const int kt0 = t << 6;
    #pragma unroll
    for (int s = 0; s < 2; ++s){
      const int c = s*256 + tid;            // 0..511 16B-chunks
      const int r = c >> 3;                 // row 0..63
      const int scol = ((c & 7) << 4) ^ ((r & 7) << 4);
      gload_lds16((const char*)Kb + ((size_t)(kt0 + r)*D_)*2 + scol,
                  (char*)&Ks[buf][0] + c*16);
      gload_lds16((const char*)Vb + ((size_t)r*T_ + kt0)*2 + scol,
                  (char*)&Vs[buf][0] + c*16);
    }
  };

  // Q fragments (B-operand): lane reads Q[qw0+lr][g*8..], [32+g*8..]
  const s16x8 bq0 = *(const s16x8*)&Qb[(size_t)(qw0+lr)*D_ + g*8];
  const s16x8 bq1 = *(const s16x8*)&Qb[(size_t)(qw0+lr)*D_ + 32 + g*8];

  f32x4 yacc[4];
  #pragma unroll
  for (int dt = 0; dt < 4; ++dt) yacc[dt] = (f32x4){0.f,0.f,0.f,0.f};
  float mrun = -1e30f, lrun = 0.f;

  const int ntile = qt + 1;
  stage(0, 0);
  __syncthreads();

  for (int t = 0; t < ntile; ++t){
    const int cur = t & 1;
    if (t + 1 < ntile) stage(t + 1, cur ^ 1);   // issue next-tile loads BEFORE compute
    const int kt0 = t << 6;
    const unsigned short* Kt = &Ks[cur][0];
    const unsigned short* Vt = &Vs[cur][0];

    // ---- QK^T (S^T form): lane holds S[k = kt0+kk*16+g*4+r][q = lr]
    f32x4 s[4];
    #pragma unroll
    for (int kk = 0; kk < 4; ++kk){
      const int row = kk*16 + lr;
      const s16x8 a0 = *(const s16x8*)&Kt[row*64 + (((g*16)      ^ swz) >> 1)];
      const s16x8 a1 = *(const s16x8*)&Kt[row*64 + (((64 + g*16) ^ swz) >> 1)];
      f32x4 acc = (f32x4){0.f,0.f,0.f,0.f};
      acc = __builtin_amdgcn_mfma_f32_16x16x32_bf16(a0, bq0, acc, 0, 0, 0);
      acc = __builtin_amdgcn_mfma_f32_16x16x32_bf16(a1, bq1, acc, 0, 0, 0);
      s[kk] = acc;
    }

    // ---- causal mask (only the diagonal tile needs it; wave-uniform branch)
    if (kt0 + 63 > qw0){
      #pragma unroll
      for (int kk = 0; kk < 4; ++kk)
        #pragma unroll
        for (int r = 0; r < 4; ++r)
          if (kt0 + kk*16 + g*4 + r > qrow) s[kk][r] = -1e30f;
    }

    // ---- online softmax, fully in-lane + 2+2 shuffles
    float mx = -1e30f;
    #pragma unroll
    for (int kk = 0; kk < 4; ++kk)
      #pragma unroll
      for (int r = 0; r < 4; ++r) mx = fmaxf(mx, s[kk][r]);
    mx = fmaxf(mx, __shfl_xor(mx, 16, 64));
    mx = fmaxf(mx, __shfl_xor(mx, 32, 64));
    const float mnew = fmaxf(mrun, mx);
    const float corr = __expf(mrun - mnew);
    mrun = mnew;

    float rs = 0.f;
    u16x4 w[4];
    #pragma unroll
    for (int kk = 0; kk < 4; ++kk)
      #pragma unroll
      for (int r = 0; r < 4; ++r){
        const float e = __expf(s[kk][r] - mnew);
        rs += e;
        w[kk][r] = f2bf(e);
      }
    rs += __shfl_xor(rs, 16, 64);
    rs += __shfl_xor(rs, 32, 64);
    lrun = lrun * corr + rs;

    // ---- P re-fragment via per-wave LDS [q][64k], swizzled rows
    #pragma unroll
    for (int kk = 0; kk < 4; ++kk)
      *(u16x4*)&Pw[lr*64 + (((kk*32 + g*8) ^ swz) >> 1)] = w[kk];
    asm volatile("" ::: "memory");
    const s16x8 p0 = *(const s16x8*)&Pw[lr*64 + (((g*16)      ^ swz) >> 1)];
    const s16x8 p1 = *(const s16x8*)&Pw[lr*64 + (((64 + g*16) ^ swz) >> 1)];

    // ---- PV: y^T += V^T @ P
    #pragma unroll
    for (int dt = 0; dt < 4; ++dt){
      const int vrow = dt*16 + lr;
      const s16x8 v0 = *(const s16x8*)&Vt[vrow*64 + (((g*16)      ^ swz) >> 1)];
      const s16x8 v1 = *(const s16x8*)&Vt[vrow*64 + (((64 + g*16) ^ swz) >> 1)];
      f32x4 y = yacc[dt];
      #pragma unroll
      for (int r = 0; r < 4; ++r) y[r] *= corr;
      y = __builtin_amdgcn_mfma_f32_16x16x32_bf16(v0, p0, y, 0, 0, 0);
      y = __builtin_amdgcn_mfma_f32_16x16x32_bf16(v1, p1, y, 0, 0, 0);
      yacc[dt] = y;
    }

    __syncthreads();   // drains vmcnt (stage loads) + protects buffer swap
  }

  // y^T layout: lane holds y[q=lr][d = dt*16 + g*4 + r]
  const int bq = bh >> 4, h = bh & 15;
  const float inv = 1.f / lrun;
  #pragma unroll
  for (int dt = 0; dt < 4; ++dt){
    u16x4 w;
    #pragma unroll
    for (int r = 0; r < 4; ++r) w[r] = f2bf(yacc[dt][r] * inv);
    *(u16x4*)&y_ws[((size_t)(bq*T_ + qw0 + lr))*C_ + h*64 + dt*16 + g*4] = w;
  }
}

extern "C" void kernel_launch(void* const* d_in, const int* in_sizes, int n_in,
                              void* d_out, int out_size, void* d_ws, size_t ws_size,
                              hipStream_t stream) {
  const float* x  = (const float*)d_in[0];
  const float* Wa = (const float*)d_in[1];
  const float* ba = (const float*)d_in[2];
  const float* Wp = (const float*)d_in[3];
  const float* bp = (const float*)d_in[4];
  float* out = (float*)d_out;

  char* ws = (char*)d_ws;
  const size_t MB = 1024u*1024u;
  unsigned short* xb  = (unsigned short*)(ws + 0);       // 16 MiB  [8192][1024] bf16
  unsigned short* wab = (unsigned short*)(ws + 16*MB);   //  6 MiB  [3072][1024]
  unsigned short* wpb = (unsigned short*)(ws + 22*MB);   //  2 MiB  [1024][1024]
  unsigned short* qws = (unsigned short*)(ws + 24*MB);   // 16 MiB  [64][2048][64]
  unsigned short* kws = (unsigned short*)(ws + 40*MB);   // 16 MiB  [64][2048][64]
  unsigned short* vT  = (unsigned short*)(ws + 56*MB);   // 16 MiB  [64][64][2048]
  unsigned short* yws = (unsigned short*)(ws + 72*MB);   // 16 MiB  [8192][1024]

  cvt_kernel<<<4096, 256, 0, stream>>>(x,  xb);
  cvt_kernel<<<1536, 256, 0, stream>>>(Wa, wab);
  cvt_kernel<<< 512, 256, 0, stream>>>(Wp, wpb);

  gemm_bt<0><<<dim3(24, 64), 256, 0, stream>>>(xb, wab, ba, 8192, 3072, 1024,
                                               qws, kws, vT, nullptr);
  attn_kernel<<<dim3(32, 64), 256, 0, stream>>>(qws, kws, vT, yws);
  gemm_bt<1><<<dim3(8, 64), 256, 0, stream>>>(yws, wpb, bp, 8192, 1024, 1024,
                                              nullptr, nullptr, nullptr, out);
}

// Round 4
// 259.509 us; speedup vs baseline: 2.2673x; 1.0351x over previous
//
#include <hip/hip_runtime.h>

typedef __attribute__((ext_vector_type(8))) short s16x8;
typedef __attribute__((ext_vector_type(4))) float f32x4;
typedef __attribute__((ext_vector_type(4))) unsigned short u16x4;

#define T_  2048
#define C_  1024
#define D_  64

__device__ __forceinline__ unsigned short f2bf(float f){
  union { float fv; unsigned int u; } v; v.fv = f;
  unsigned int r = v.u + 0x7FFFu + ((v.u >> 16) & 1u);
  return (unsigned short)(r >> 16);
}

__device__ __forceinline__ float exp2_asm(float x){
  float r; asm("v_exp_f32 %0, %1" : "=v"(r) : "v"(x)); return r;
}
__device__ __forceinline__ unsigned int cvtpk(float lo, float hi){
  unsigned int r; asm("v_cvt_pk_bf16_f32 %0, %1, %2" : "=v"(r) : "v"(lo), "v"(hi)); return r;
}

__device__ __forceinline__ void gload_lds16(const void* g, void* l){
  __builtin_amdgcn_global_load_lds(
      (const __attribute__((address_space(1))) unsigned int*)g,
      (__attribute__((address_space(3))) unsigned int*)l, 16, 0, 0);
}

// ---------------- fp32 -> bf16 convert, 8 elems/thread ----------------
__global__ __launch_bounds__(256) void cvt_kernel(const float* __restrict__ src,
                                                  unsigned short* __restrict__ dst){
  size_t i = ((size_t)blockIdx.x * 256u + threadIdx.x) * 8u;
  f32x4 a = *(const f32x4*)(src + i);
  f32x4 b = *(const f32x4*)(src + i + 4);
  s16x8 o;
  #pragma unroll
  for (int j = 0; j < 4; ++j){ o[j] = (short)f2bf(a[j]); o[4+j] = (short)f2bf(b[j]); }
  *(s16x8*)(dst + i) = o;
}

// ---------------- GEMM: C[m,n] = sum_k A[m,k]*Bw[n,k] + bias[n] ----------------
template<int MODE>
__global__ __launch_bounds__(256) void gemm_bt(
    const unsigned short* __restrict__ A, const unsigned short* __restrict__ Bw,
    const float* __restrict__ bias, int M, int N, int K,
    unsigned short* __restrict__ q_ws, unsigned short* __restrict__ k_ws,
    unsigned short* __restrict__ vT_ws, float* __restrict__ out)
{
  __shared__ unsigned short As[128*32];
  __shared__ unsigned short Bs[128*32];
  const int tid = threadIdx.x;
  const int lane = tid & 63, wid = tid >> 6;
  const int g = lane >> 4, lr = lane & 15;
  const int m0 = blockIdx.y * 128, n0 = blockIdx.x * 128;
  const int wr = wid >> 1, wc = wid & 1;

  f32x4 acc[4][4];
  #pragma unroll
  for (int i = 0; i < 4; ++i)
    #pragma unroll
    for (int j = 0; j < 4; ++j) acc[i][j] = (f32x4){0.f,0.f,0.f,0.f};

  const int nk = K >> 5;
  for (int kt = 0; kt < nk; ++kt){
    const int k0 = kt << 5;
    #pragma unroll
    for (int j = 0; j < 2; ++j){
      const int c = wid*128 + j*64 + lane;
      const int row = c >> 2, kc = c & 3;
      gload_lds16((const char*)A  + (((size_t)(m0+row))*K + k0)*2 + kc*16,
                  (char*)As + (size_t)(wid*128 + j*64)*16);
      gload_lds16((const char*)Bw + (((size_t)(n0+row))*K + k0)*2 + kc*16,
                  (char*)Bs + (size_t)(wid*128 + j*64)*16);
    }
    __syncthreads();
    s16x8 af[4], bf[4];
    #pragma unroll
    for (int i = 0; i < 4; ++i)
      af[i] = *(const s16x8*)&As[(wr*64 + i*16 + lr)*32 + g*8];
    #pragma unroll
    for (int j = 0; j < 4; ++j)
      bf[j] = *(const s16x8*)&Bs[(wc*64 + j*16 + lr)*32 + g*8];
    #pragma unroll
    for (int i = 0; i < 4; ++i)
      #pragma unroll
      for (int j = 0; j < 4; ++j)
        acc[i][j] = __builtin_amdgcn_mfma_f32_16x16x32_bf16(af[i], bf[j], acc[i][j], 0, 0, 0);
    __syncthreads();
  }

  #pragma unroll
  for (int i = 0; i < 4; ++i){
    #pragma unroll
    for (int j = 0; j < 4; ++j){
      const int n = n0 + wc*64 + j*16 + lr;
      const float bv = bias[n];
      #pragma unroll
      for (int r = 0; r < 4; ++r){
        const int m = m0 + wr*64 + i*16 + g*4 + r;
        const float val = acc[i][j][r] + bv;
        if (MODE == 0){
          const int which = n >> 10;
          const int cc = n & 1023;
          const int h = cc >> 6, d = cc & 63;
          const int bq = m >> 11, t = m & 2047;
          const int bh = bq*16 + h;
          // q pre-scaled by log2(e)/64 so attention works in exp2 domain
          if (which == 0)      q_ws[((size_t)bh*T_ + t)*D_ + d] = f2bf(val * 0.022542110013890054f);
          else if (which == 1) k_ws[((size_t)bh*T_ + t)*D_ + d] = f2bf(val);
          else                 vT_ws[((size_t)bh*D_ + d)*T_ + t] = f2bf(val);
        } else {
          out[(size_t)m*N + n] = val;
        }
      }
    }
  }
}

// ---------------- flash attention v4 ----------------
// Block = 4 waves = 64 queries. K/V^T double-buffered in LDS (32 KB total);
// P tile ALIASES Ks[cur] (dead after QK^T; raw s_barrier separates last K-read
// from first P-write without draining vmcnt, so staged loads stay in flight).
// Softmax in exp2 domain (log2e folded into q); row-sum l via all-ones MFMA;
// defer-max (THR=8 -> P<=256); P packed with v_cvt_pk_bf16_f32.
__global__ __launch_bounds__(256, 5) void attn_kernel(
    const unsigned short* __restrict__ q_ws, const unsigned short* __restrict__ k_ws,
    const unsigned short* __restrict__ vT_ws, unsigned short* __restrict__ y_ws)
{
  __shared__ __align__(16) unsigned short Ks[2][64*64];   // [key][d]  8KB x2 (P aliases Ks[cur])
  __shared__ __align__(16) unsigned short Vs[2][64*64];   // [d][key]  8KB x2

  const int tid = threadIdx.x;
  const int lane = tid & 63, wid = tid >> 6;
  const int g = lane >> 4, lr = lane & 15;
  const int qt = (int)gridDim.x - 1 - (int)blockIdx.x;    // heavy q-tiles first
  const int bh = blockIdx.y;
  const int qw0 = qt*64 + wid*16;
  const int qrow = qw0 + lr;
  const int swz = (lr & 7) << 4;

  const unsigned short* Qb = q_ws  + (size_t)bh*T_*D_;
  const unsigned short* Kb = k_ws  + (size_t)bh*T_*D_;
  const unsigned short* Vb = vT_ws + (size_t)bh*D_*T_;

  auto stage = [&](int t, int buf){
    const int kt0 = t << 6;
    #pragma unroll
    for (int s = 0; s < 2; ++s){
      const int c = s*256 + tid;
      const int r = c >> 3;
      const int scol = ((c & 7) << 4) ^ ((r & 7) << 4);
      gload_lds16((const char*)Kb + ((size_t)(kt0 + r)*D_)*2 + scol,
                  (char*)&Ks[buf][0] + c*16);
      gload_lds16((const char*)Vb + ((size_t)r*T_ + kt0)*2 + scol,
                  (char*)&Vs[buf][0] + c*16);
    }
  };

  const s16x8 bq0 = *(const s16x8*)&Qb[(size_t)(qw0+lr)*D_ + g*8];
  const s16x8 bq1 = *(const s16x8*)&Qb[(size_t)(qw0+lr)*D_ + 32 + g*8];

  // all-ones bf16 A-fragment for the row-sum MFMA
  s16x8 ones;
  #pragma unroll
  for (int j = 0; j < 8; ++j) ones[j] = (short)0x3F80;

  f32x4 yacc[4];
  #pragma unroll
  for (int dt = 0; dt < 4; ++dt) yacc[dt] = (f32x4){0.f,0.f,0.f,0.f};
  f32x4 lacc = (f32x4){0.f,0.f,0.f,0.f};                 // element 0 = running l (exp2 dom)
  float mrun = -1e30f;

  const int ntile = qt + 1;
  stage(0, 0);
  __syncthreads();

  for (int t = 0; t < ntile; ++t){
    const int cur = t & 1;
    if (t + 1 < ntile) stage(t + 1, cur ^ 1);
    const int kt0 = t << 6;
    const unsigned short* Kt = &Ks[cur][0];
    const unsigned short* Vt = &Vs[cur][0];
    unsigned short* Pw = &Ks[cur][wid*1024];             // P aliases K[cur] (dead after QK^T)

    // ---- QK^T: lane holds S[k = kt0+kk*16+g*4+r][q = lr], log2 domain
    f32x4 s[4];
    #pragma unroll
    for (int kk = 0; kk < 4; ++kk){
      const int row = kk*16 + lr;
      const s16x8 a0 = *(const s16x8*)&Kt[row*64 + (((g*16)      ^ swz) >> 1)];
      const s16x8 a1 = *(const s16x8*)&Kt[row*64 + (((64 + g*16) ^ swz) >> 1)];
      f32x4 acc = (f32x4){0.f,0.f,0.f,0.f};
      acc = __builtin_amdgcn_mfma_f32_16x16x32_bf16(a0, bq0, acc, 0, 0, 0);
      acc = __builtin_amdgcn_mfma_f32_16x16x32_bf16(a1, bq1, acc, 0, 0, 0);
      s[kk] = acc;
    }

    // ---- causal mask (diagonal tile only; wave-uniform branch)
    if (kt0 + 63 > qw0){
      #pragma unroll
      for (int kk = 0; kk < 4; ++kk)
        #pragma unroll
        for (int r = 0; r < 4; ++r)
          if (kt0 + kk*16 + g*4 + r > qrow) s[kk][r] = -1e30f;
    }

    // ---- per-q max (tree) + cross-group reduce
    float m01 = fmaxf(fmaxf(s[0][0], s[0][1]), fmaxf(s[0][2], s[0][3]));
    float m23 = fmaxf(fmaxf(s[1][0], s[1][1]), fmaxf(s[1][2], s[1][3]));
    float m45 = fmaxf(fmaxf(s[2][0], s[2][1]), fmaxf(s[2][2], s[2][3]));
    float m67 = fmaxf(fmaxf(s[3][0], s[3][1]), fmaxf(s[3][2], s[3][3]));
    float mx = fmaxf(fmaxf(m01, m23), fmaxf(m45, m67));
    mx = fmaxf(mx, __shfl_xor(mx, 16, 64));
    mx = fmaxf(mx, __shfl_xor(mx, 32, 64));

    // ---- defer-max: rescale only when some q's max grew past THR=8 (P <= 2^8)
    if (!__all(mx <= mrun + 8.f)){
      const float mnew = fmaxf(mrun, mx);
      const float corr = exp2_asm(mrun - mnew);
      mrun = mnew;
      lacc[0] *= corr;
      #pragma unroll
      for (int dt = 0; dt < 4; ++dt)
        #pragma unroll
        for (int r = 0; r < 4; ++r) yacc[dt][r] *= corr;
    }

    // ---- P = exp2(s - mrun), packed to bf16 pairs
    union { unsigned int u[2]; u16x4 v; } pk[4];
    #pragma unroll
    for (int kk = 0; kk < 4; ++kk){
      const float e0 = exp2_asm(s[kk][0] - mrun);
      const float e1 = exp2_asm(s[kk][1] - mrun);
      const float e2 = exp2_asm(s[kk][2] - mrun);
      const float e3 = exp2_asm(s[kk][3] - mrun);
      pk[kk].u[0] = cvtpk(e0, e1);
      pk[kk].u[1] = cvtpk(e2, e3);
    }

    // ---- wait all waves done reading K[cur] (lgkm already drained per-wave
    //      before each MFMA); raw barrier does NOT drain vmcnt -> staging flows
    asm volatile("s_barrier" ::: "memory");

    #pragma unroll
    for (int kk = 0; kk < 4; ++kk)
      *(u16x4*)&Pw[lr*64 + (((kk*32 + g*8) ^ swz) >> 1)] = pk[kk].v;
    asm volatile("" ::: "memory");
    const s16x8 p0 = *(const s16x8*)&Pw[lr*64 + (((g*16)      ^ swz) >> 1)];
    const s16x8 p1 = *(const s16x8*)&Pw[lr*64 + (((64 + g*16) ^ swz) >> 1)];

    // ---- row-sum l via all-ones MFMA (replicated over rows; keep element 0)
    lacc = __builtin_amdgcn_mfma_f32_16x16x32_bf16(ones, p0, lacc, 0, 0, 0);
    lacc = __builtin_amdgcn_mfma_f32_16x16x32_bf16(ones, p1, lacc, 0, 0, 0);

    // ---- PV: y^T += V^T @ P
    #pragma unroll
    for (int dt = 0; dt < 4; ++dt){
      const int vrow = dt*16 + lr;
      const s16x8 v0 = *(const s16x8*)&Vt[vrow*64 + (((g*16)      ^ swz) >> 1)];
      const s16x8 v1 = *(const s16x8*)&Vt[vrow*64 + (((64 + g*16) ^ swz) >> 1)];
      yacc[dt] = __builtin_amdgcn_mfma_f32_16x16x32_bf16(v0, p0, yacc[dt], 0, 0, 0);
      yacc[dt] = __builtin_amdgcn_mfma_f32_16x16x32_bf16(v1, p1, yacc[dt], 0, 0, 0);
    }

    __syncthreads();   // drains vmcnt (stage t+1) + protects buffer swap / P region
  }

  const int bq = bh >> 4, h = bh & 15;
  const float inv = 1.f / lacc[0];
  #pragma unroll
  for (int dt = 0; dt < 4; ++dt){
    union { unsigned int u[2]; u16x4 v; } w;
    w.u[0] = cvtpk(yacc[dt][0]*inv, yacc[dt][1]*inv);
    w.u[1] = cvtpk(yacc[dt][2]*inv, yacc[dt][3]*inv);
    *(u16x4*)&y_ws[((size_t)(bq*T_ + qw0 + lr))*C_ + h*64 + dt*16 + g*4] = w.v;
  }
}

extern "C" void kernel_launch(void* const* d_in, const int* in_sizes, int n_in,
                              void* d_out, int out_size, void* d_ws, size_t ws_size,
                              hipStream_t stream) {
  const float* x  = (const float*)d_in[0];
  const float* Wa = (const float*)d_in[1];
  const float* ba = (const float*)d_in[2];
  const float* Wp = (const float*)d_in[3];
  const float* bp = (const float*)d_in[4];
  float* out = (float*)d_out;

  char* ws = (char*)d_ws;
  const size_t MB = 1024u*1024u;
  unsigned short* xb  = (unsigned short*)(ws + 0);       // 16 MiB  [8192][1024] bf16
  unsigned short* wab = (unsigned short*)(ws + 16*MB);   //  6 MiB  [3072][1024]
  unsigned short* wpb = (unsigned short*)(ws + 22*MB);   //  2 MiB  [1024][1024]
  unsigned short* qws = (unsigned short*)(ws + 24*MB);   // 16 MiB  [64][2048][64]
  unsigned short* kws = (unsigned short*)(ws + 40*MB);   // 16 MiB  [64][2048][64]
  unsigned short* vT  = (unsigned short*)(ws + 56*MB);   // 16 MiB  [64][64][2048]
  unsigned short* yws = (unsigned short*)(ws + 72*MB);   // 16 MiB  [8192][1024]

  cvt_kernel<<<4096, 256, 0, stream>>>(x,  xb);
  cvt_kernel<<<1536, 256, 0, stream>>>(Wa, wab);
  cvt_kernel<<< 512, 256, 0, stream>>>(Wp, wpb);

  gemm_bt<0><<<dim3(24, 64), 256, 0, stream>>>(xb, wab, ba, 8192, 3072, 1024,
                                               qws, kws, vT, nullptr);
  attn_kernel<<<dim3(32, 64), 256, 0, stream>>>(qws, kws, vT, yws);
  gemm_bt<1><<<dim3(8, 64), 256, 0, stream>>>(yws, wpb, bp, 8192, 1024, 1024,
                                              nullptr, nullptr, nullptr, out);
}

// Round 5
// 216.062 us; speedup vs baseline: 2.7232x; 1.2011x over previous
//
#include <hip/hip_runtime.h>

typedef __attribute__((ext_vector_type(8))) short s16x8;
typedef __attribute__((ext_vector_type(4))) float f32x4;
typedef __attribute__((ext_vector_type(4))) unsigned short u16x4;

#define T_  2048
#define C_  1024
#define D_  64

__device__ __forceinline__ unsigned short f2bf(float f){
  union { float fv; unsigned int u; } v; v.fv = f;
  unsigned int r = v.u + 0x7FFFu + ((v.u >> 16) & 1u);
  return (unsigned short)(r >> 16);
}

__device__ __forceinline__ float exp2_asm(float x){
  float r; asm("v_exp_f32 %0, %1" : "=v"(r) : "v"(x)); return r;
}
__device__ __forceinline__ unsigned int cvtpk(float lo, float hi){
  unsigned int r; asm("v_cvt_pk_bf16_f32 %0, %1, %2" : "=v"(r) : "v"(lo), "v"(hi)); return r;
}

__device__ __forceinline__ void gload_lds16(const void* g, void* l){
  __builtin_amdgcn_global_load_lds(
      (const __attribute__((address_space(1))) unsigned int*)g,
      (__attribute__((address_space(3))) unsigned int*)l, 16, 0, 0);
}

// ---------------- fp32 -> bf16 convert, 8 elems/thread ----------------
__global__ __launch_bounds__(256) void cvt_kernel(const float* __restrict__ src,
                                                  unsigned short* __restrict__ dst){
  size_t i = ((size_t)blockIdx.x * 256u + threadIdx.x) * 8u;
  f32x4 a = *(const f32x4*)(src + i);
  f32x4 b = *(const f32x4*)(src + i + 4);
  s16x8 o;
  #pragma unroll
  for (int j = 0; j < 4; ++j){ o[j] = (short)f2bf(a[j]); o[4+j] = (short)f2bf(b[j]); }
  *(s16x8*)(dst + i) = o;
}

// ---------------- GEMM: C[m,n] = sum_k A[m,k]*Bw[n,k] + bias[n] ----------------
template<int MODE>
__global__ __launch_bounds__(256) void gemm_bt(
    const unsigned short* __restrict__ A, const unsigned short* __restrict__ Bw,
    const float* __restrict__ bias, int M, int N, int K,
    unsigned short* __restrict__ q_ws, unsigned short* __restrict__ k_ws,
    unsigned short* __restrict__ vT_ws, float* __restrict__ out)
{
  __shared__ unsigned short As[128*32];
  __shared__ unsigned short Bs[128*32];
  const int tid = threadIdx.x;
  const int lane = tid & 63, wid = tid >> 6;
  const int g = lane >> 4, lr = lane & 15;
  const int m0 = blockIdx.y * 128, n0 = blockIdx.x * 128;
  const int wr = wid >> 1, wc = wid & 1;

  f32x4 acc[4][4];
  #pragma unroll
  for (int i = 0; i < 4; ++i)
    #pragma unroll
    for (int j = 0; j < 4; ++j) acc[i][j] = (f32x4){0.f,0.f,0.f,0.f};

  const int nk = K >> 5;
  for (int kt = 0; kt < nk; ++kt){
    const int k0 = kt << 5;
    #pragma unroll
    for (int j = 0; j < 2; ++j){
      const int c = wid*128 + j*64 + lane;
      const int row = c >> 2, kc = c & 3;
      gload_lds16((const char*)A  + (((size_t)(m0+row))*K + k0)*2 + kc*16,
                  (char*)As + (size_t)(wid*128 + j*64)*16);
      gload_lds16((const char*)Bw + (((size_t)(n0+row))*K + k0)*2 + kc*16,
                  (char*)Bs + (size_t)(wid*128 + j*64)*16);
    }
    __syncthreads();
    s16x8 af[4], bf[4];
    #pragma unroll
    for (int i = 0; i < 4; ++i)
      af[i] = *(const s16x8*)&As[(wr*64 + i*16 + lr)*32 + g*8];
    #pragma unroll
    for (int j = 0; j < 4; ++j)
      bf[j] = *(const s16x8*)&Bs[(wc*64 + j*16 + lr)*32 + g*8];
    #pragma unroll
    for (int i = 0; i < 4; ++i)
      #pragma unroll
      for (int j = 0; j < 4; ++j)
        acc[i][j] = __builtin_amdgcn_mfma_f32_16x16x32_bf16(af[i], bf[j], acc[i][j], 0, 0, 0);
    __syncthreads();
  }

  #pragma unroll
  for (int i = 0; i < 4; ++i){
    #pragma unroll
    for (int j = 0; j < 4; ++j){
      const int n = n0 + wc*64 + j*16 + lr;
      const float bv = bias[n];
      #pragma unroll
      for (int r = 0; r < 4; ++r){
        const int m = m0 + wr*64 + i*16 + g*4 + r;
        const float val = acc[i][j][r] + bv;
        if (MODE == 0){
          const int which = n >> 10;
          const int cc = n & 1023;
          const int h = cc >> 6, d = cc & 63;
          const int bq = m >> 11, t = m & 2047;
          const int bh = bq*16 + h;
          // q pre-scaled by log2(e)/64 so attention works in exp2 domain
          if (which == 0)      q_ws[((size_t)bh*T_ + t)*D_ + d] = f2bf(val * 0.022542110013890054f);
          else if (which == 1) k_ws[((size_t)bh*T_ + t)*D_ + d] = f2bf(val);
          else                 vT_ws[((size_t)bh*D_ + d)*T_ + t] = f2bf(val);
        } else {
          out[(size_t)m*N + n] = val;
        }
      }
    }
  }
}

// ---------------- flash attention v5: balanced pairs, shared K/V staging ----------------
// Block handles q-tiles A=p and B=31-p: every block = 33 tile-units of work
// (1024 equal blocks = exactly 4/CU, no drain tail). A's key range is a prefix
// of B's -> both share staged K/V AND the K fragments. P aliases Ks[cur] after
// a raw s_barrier (all QK^T K-reads done; vmcnt staging stays in flight).
__global__ __launch_bounds__(256, 4) void attn_kernel(
    const unsigned short* __restrict__ q_ws, const unsigned short* __restrict__ k_ws,
    const unsigned short* __restrict__ vT_ws, unsigned short* __restrict__ y_ws)
{
  __shared__ __align__(16) unsigned short Ks[2][64*64];   // [key][d]  8KB x2 (P aliases Ks[cur])
  __shared__ __align__(16) unsigned short Vs[2][64*64];   // [d][key]  8KB x2

  const int tid = threadIdx.x;
  const int lane = tid & 63, wid = tid >> 6;
  const int g = lane >> 4, lr = lane & 15;
  const int orig = (int)blockIdx.x;
  const int wgid = (orig & 7) * 128 + (orig >> 3);        // XCD-chunk: same-bh blocks colocate on one L2
  const int p  = wgid & 15;
  const int bh = wgid >> 4;
  const int qwA = p*64 + wid*16,  qwB = (31 - p)*64 + wid*16;
  const int qrowA = qwA + lr,     qrowB = qwB + lr;
  const int swz = (lr & 7) << 4;

  const unsigned short* Qb = q_ws  + (size_t)bh*T_*D_;
  const unsigned short* Kb = k_ws  + (size_t)bh*T_*D_;
  const unsigned short* Vb = vT_ws + (size_t)bh*D_*T_;

  auto stage = [&](int t, int buf){
    const int kt0 = t << 6;
    #pragma unroll
    for (int s = 0; s < 2; ++s){
      const int c = s*256 + tid;
      const int r = c >> 3;
      const int scol = ((c & 7) << 4) ^ ((r & 7) << 4);
      gload_lds16((const char*)Kb + ((size_t)(kt0 + r)*D_)*2 + scol,
                  (char*)&Ks[buf][0] + c*16);
      gload_lds16((const char*)Vb + ((size_t)r*T_ + kt0)*2 + scol,
                  (char*)&Vs[buf][0] + c*16);
    }
  };

  const s16x8 bqA0 = *(const s16x8*)&Qb[(size_t)(qwA+lr)*D_ + g*8];
  const s16x8 bqA1 = *(const s16x8*)&Qb[(size_t)(qwA+lr)*D_ + 32 + g*8];
  const s16x8 bqB0 = *(const s16x8*)&Qb[(size_t)(qwB+lr)*D_ + g*8];
  const s16x8 bqB1 = *(const s16x8*)&Qb[(size_t)(qwB+lr)*D_ + 32 + g*8];

  s16x8 ones;
  #pragma unroll
  for (int j = 0; j < 8; ++j) ones[j] = (short)0x3F80;

  f32x4 yA[4], yB[4];
  #pragma unroll
  for (int dt = 0; dt < 4; ++dt){ yA[dt] = (f32x4){0.f,0.f,0.f,0.f}; yB[dt] = (f32x4){0.f,0.f,0.f,0.f}; }
  f32x4 lacA = (f32x4){0.f,0.f,0.f,0.f}, lacB = (f32x4){0.f,0.f,0.f,0.f};
  float mA = -1e30f, mB = -1e30f;

  const int ntA = p + 1, ntB = 32 - p;
  stage(0, 0);
  __syncthreads();

  for (int t = 0; t < ntB; ++t){
    const int cur = t & 1;
    if (t + 1 < ntB) stage(t + 1, cur ^ 1);
    const int kt0 = t << 6;
    const unsigned short* Kt = &Ks[cur][0];
    const unsigned short* Vt = &Vs[cur][0];
    unsigned short* Pw = &Ks[cur][wid*1024];
    const bool actA = (t < ntA);                 // wave-uniform

    // ---- QK^T for B (and A): shared K fragments
    f32x4 sB[4], sA[4];
    #pragma unroll
    for (int kk = 0; kk < 4; ++kk){
      const int row = kk*16 + lr;
      const s16x8 a0 = *(const s16x8*)&Kt[row*64 + (((g*16)      ^ swz) >> 1)];
      const s16x8 a1 = *(const s16x8*)&Kt[row*64 + (((64 + g*16) ^ swz) >> 1)];
      f32x4 acc = (f32x4){0.f,0.f,0.f,0.f};
      acc = __builtin_amdgcn_mfma_f32_16x16x32_bf16(a0, bqB0, acc, 0, 0, 0);
      acc = __builtin_amdgcn_mfma_f32_16x16x32_bf16(a1, bqB1, acc, 0, 0, 0);
      sB[kk] = acc;
      if (actA){
        f32x4 acc2 = (f32x4){0.f,0.f,0.f,0.f};
        acc2 = __builtin_amdgcn_mfma_f32_16x16x32_bf16(a0, bqA0, acc2, 0, 0, 0);
        acc2 = __builtin_amdgcn_mfma_f32_16x16x32_bf16(a1, bqA1, acc2, 0, 0, 0);
        sA[kk] = acc2;
      }
    }

    // ---- softmax B (pre-barrier: registers only)
    if (kt0 + 63 > qwB){
      #pragma unroll
      for (int kk = 0; kk < 4; ++kk)
        #pragma unroll
        for (int r = 0; r < 4; ++r)
          if (kt0 + kk*16 + g*4 + r > qrowB) sB[kk][r] = -1e30f;
    }
    {
      float m01 = fmaxf(fmaxf(sB[0][0], sB[0][1]), fmaxf(sB[0][2], sB[0][3]));
      float m23 = fmaxf(fmaxf(sB[1][0], sB[1][1]), fmaxf(sB[1][2], sB[1][3]));
      float m45 = fmaxf(fmaxf(sB[2][0], sB[2][1]), fmaxf(sB[2][2], sB[2][3]));
      float m67 = fmaxf(fmaxf(sB[3][0], sB[3][1]), fmaxf(sB[3][2], sB[3][3]));
      float mx = fmaxf(fmaxf(m01, m23), fmaxf(m45, m67));
      mx = fmaxf(mx, __shfl_xor(mx, 16, 64));
      mx = fmaxf(mx, __shfl_xor(mx, 32, 64));
      if (!__all(mx <= mB + 8.f)){
        const float mnew = fmaxf(mB, mx);
        const float corr = exp2_asm(mB - mnew);
        mB = mnew;
        lacB[0] *= corr;
        #pragma unroll
        for (int dt = 0; dt < 4; ++dt)
          #pragma unroll
          for (int r = 0; r < 4; ++r) yB[dt][r] *= corr;
      }
    }
    union { unsigned int u[2]; u16x4 v; } pkB[4];
    #pragma unroll
    for (int kk = 0; kk < 4; ++kk){
      const float e0 = exp2_asm(sB[kk][0] - mB);
      const float e1 = exp2_asm(sB[kk][1] - mB);
      const float e2 = exp2_asm(sB[kk][2] - mB);
      const float e3 = exp2_asm(sB[kk][3] - mB);
      pkB[kk].u[0] = cvtpk(e0, e1);
      pkB[kk].u[1] = cvtpk(e2, e3);
    }

    // ---- all waves done reading Ks[cur] (A's QK^T included); vmcnt stays in flight
    asm volatile("s_barrier" ::: "memory");

    // ---- P/PV for B
    #pragma unroll
    for (int kk = 0; kk < 4; ++kk)
      *(u16x4*)&Pw[lr*64 + (((kk*32 + g*8) ^ swz) >> 1)] = pkB[kk].v;
    asm volatile("" ::: "memory");
    {
      const s16x8 p0 = *(const s16x8*)&Pw[lr*64 + (((g*16)      ^ swz) >> 1)];
      const s16x8 p1 = *(const s16x8*)&Pw[lr*64 + (((64 + g*16) ^ swz) >> 1)];
      lacB = __builtin_amdgcn_mfma_f32_16x16x32_bf16(ones, p0, lacB, 0, 0, 0);
      lacB = __builtin_amdgcn_mfma_f32_16x16x32_bf16(ones, p1, lacB, 0, 0, 0);
      #pragma unroll
      for (int dt = 0; dt < 4; ++dt){
        const int vrow = dt*16 + lr;
        const s16x8 v0 = *(const s16x8*)&Vt[vrow*64 + (((g*16)      ^ swz) >> 1)];
        const s16x8 v1 = *(const s16x8*)&Vt[vrow*64 + (((64 + g*16) ^ swz) >> 1)];
        yB[dt] = __builtin_amdgcn_mfma_f32_16x16x32_bf16(v0, p0, yB[dt], 0, 0, 0);
        yB[dt] = __builtin_amdgcn_mfma_f32_16x16x32_bf16(v1, p1, yB[dt], 0, 0, 0);
      }
    }

    // ---- softmax + P/PV for A (P region is per-wave private: in-wave order only)
    if (actA){
      if (kt0 + 63 > qwA){
        #pragma unroll
        for (int kk = 0; kk < 4; ++kk)
          #pragma unroll
          for (int r = 0; r < 4; ++r)
            if (kt0 + kk*16 + g*4 + r > qrowA) sA[kk][r] = -1e30f;
      }
      float m01 = fmaxf(fmaxf(sA[0][0], sA[0][1]), fmaxf(sA[0][2], sA[0][3]));
      float m23 = fmaxf(fmaxf(sA[1][0], sA[1][1]), fmaxf(sA[1][2], sA[1][3]));
      float m45 = fmaxf(fmaxf(sA[2][0], sA[2][1]), fmaxf(sA[2][2], sA[2][3]));
      float m67 = fmaxf(fmaxf(sA[3][0], sA[3][1]), fmaxf(sA[3][2], sA[3][3]));
      float mx = fmaxf(fmaxf(m01, m23), fmaxf(m45, m67));
      mx = fmaxf(mx, __shfl_xor(mx, 16, 64));
      mx = fmaxf(mx, __shfl_xor(mx, 32, 64));
      if (!__all(mx <= mA + 8.f)){
        const float mnew = fmaxf(mA, mx);
        const float corr = exp2_asm(mA - mnew);
        mA = mnew;
        lacA[0] *= corr;
        #pragma unroll
        for (int dt = 0; dt < 4; ++dt)
          #pragma unroll
          for (int r = 0; r < 4; ++r) yA[dt][r] *= corr;
      }
      union { unsigned int u[2]; u16x4 v; } pkA[4];
      #pragma unroll
      for (int kk = 0; kk < 4; ++kk){
        const float e0 = exp2_asm(sA[kk][0] - mA);
        const float e1 = exp2_asm(sA[kk][1] - mA);
        const float e2 = exp2_asm(sA[kk][2] - mA);
        const float e3 = exp2_asm(sA[kk][3] - mA);
        pkA[kk].u[0] = cvtpk(e0, e1);
        pkA[kk].u[1] = cvtpk(e2, e3);
      }
      asm volatile("" ::: "memory");
      #pragma unroll
      for (int kk = 0; kk < 4; ++kk)
        *(u16x4*)&Pw[lr*64 + (((kk*32 + g*8) ^ swz) >> 1)] = pkA[kk].v;
      asm volatile("" ::: "memory");
      const s16x8 p0 = *(const s16x8*)&Pw[lr*64 + (((g*16)      ^ swz) >> 1)];
      const s16x8 p1 = *(const s16x8*)&Pw[lr*64 + (((64 + g*16) ^ swz) >> 1)];
      lacA = __builtin_amdgcn_mfma_f32_16x16x32_bf16(ones, p0, lacA, 0, 0, 0);
      lacA = __builtin_amdgcn_mfma_f32_16x16x32_bf16(ones, p1, lacA, 0, 0, 0);
      #pragma unroll
      for (int dt = 0; dt < 4; ++dt){
        const int vrow = dt*16 + lr;
        const s16x8 v0 = *(const s16x8*)&Vt[vrow*64 + (((g*16)      ^ swz) >> 1)];
        const s16x8 v1 = *(const s16x8*)&Vt[vrow*64 + (((64 + g*16) ^ swz) >> 1)];
        yA[dt] = __builtin_amdgcn_mfma_f32_16x16x32_bf16(v0, p0, yA[dt], 0, 0, 0);
        yA[dt] = __builtin_amdgcn_mfma_f32_16x16x32_bf16(v1, p1, yA[dt], 0, 0, 0);
      }
    }

    __syncthreads();   // drains vmcnt (stage t+1) + protects buffer swap / P region
  }

  const int bq = bh >> 4, h = bh & 15;
  {
    const float inv = 1.f / lacB[0];
    #pragma unroll
    for (int dt = 0; dt < 4; ++dt){
      union { unsigned int u[2]; u16x4 v; } w;
      w.u[0] = cvtpk(yB[dt][0]*inv, yB[dt][1]*inv);
      w.u[1] = cvtpk(yB[dt][2]*inv, yB[dt][3]*inv);
      *(u16x4*)&y_ws[((size_t)(bq*T_ + qwB + lr))*C_ + h*64 + dt*16 + g*4] = w.v;
    }
  }
  {
    const float inv = 1.f / lacA[0];
    #pragma unroll
    for (int dt = 0; dt < 4; ++dt){
      union { unsigned int u[2]; u16x4 v; } w;
      w.u[0] = cvtpk(yA[dt][0]*inv, yA[dt][1]*inv);
      w.u[1] = cvtpk(yA[dt][2]*inv, yA[dt][3]*inv);
      *(u16x4*)&y_ws[((size_t)(bq*T_ + qwA + lr))*C_ + h*64 + dt*16 + g*4] = w.v;
    }
  }
}

extern "C" void kernel_launch(void* const* d_in, const int* in_sizes, int n_in,
                              void* d_out, int out_size, void* d_ws, size_t ws_size,
                              hipStream_t stream) {
  const float* x  = (const float*)d_in[0];
  const float* Wa = (const float*)d_in[1];
  const float* ba = (const float*)d_in[2];
  const float* Wp = (const float*)d_in[3];
  const float* bp = (const float*)d_in[4];
  float* out = (float*)d_out;

  char* ws = (char*)d_ws;
  const size_t MB = 1024u*1024u;
  unsigned short* xb  = (unsigned short*)(ws + 0);       // 16 MiB  [8192][1024] bf16
  unsigned short* wab = (unsigned short*)(ws + 16*MB);   //  6 MiB  [3072][1024]
  unsigned short* wpb = (unsigned short*)(ws + 22*MB);   //  2 MiB  [1024][1024]
  unsigned short* qws = (unsigned short*)(ws + 24*MB);   // 16 MiB  [64][2048][64]
  unsigned short* kws = (unsigned short*)(ws + 40*MB);   // 16 MiB  [64][2048][64]
  unsigned short* vT  = (unsigned short*)(ws + 56*MB);   // 16 MiB  [64][64][2048]
  unsigned short* yws = (unsigned short*)(ws + 72*MB);   // 16 MiB  [8192][1024]

  cvt_kernel<<<4096, 256, 0, stream>>>(x,  xb);
  cvt_kernel<<<1536, 256, 0, stream>>>(Wa, wab);
  cvt_kernel<<< 512, 256, 0, stream>>>(Wp, wpb);

  gemm_bt<0><<<dim3(24, 64), 256, 0, stream>>>(xb, wab, ba, 8192, 3072, 1024,
                                               qws, kws, vT, nullptr);
  attn_kernel<<<dim3(1024), 256, 0, stream>>>(qws, kws, vT, yws);
  gemm_bt<1><<<dim3(8, 64), 256, 0, stream>>>(yws, wpb, bp, 8192, 1024, 1024,
                                              nullptr, nullptr, nullptr, out);
}

// Round 6
// 207.681 us; speedup vs baseline: 2.8331x; 1.0404x over previous
//
#include <hip/hip_runtime.h>

typedef __attribute__((ext_vector_type(8))) short s16x8;
typedef __attribute__((ext_vector_type(4))) float f32x4;
typedef __attribute__((ext_vector_type(4))) unsigned short u16x4;

#define T_  2048
#define C_  1024
#define D_  64

__device__ __forceinline__ unsigned short f2bf(float f){
  union { float fv; unsigned int u; } v; v.fv = f;
  unsigned int r = v.u + 0x7FFFu + ((v.u >> 16) & 1u);
  return (unsigned short)(r >> 16);
}

__device__ __forceinline__ float exp2_asm(float x){
  float r; asm("v_exp_f32 %0, %1" : "=v"(r) : "v"(x)); return r;
}
__device__ __forceinline__ unsigned int cvtpk(float lo, float hi){
  unsigned int r; asm("v_cvt_pk_bf16_f32 %0, %1, %2" : "=v"(r) : "v"(lo), "v"(hi)); return r;
}

__device__ __forceinline__ void gload_lds16(const void* g, void* l){
  __builtin_amdgcn_global_load_lds(
      (const __attribute__((address_space(1))) unsigned int*)g,
      (__attribute__((address_space(3))) unsigned int*)l, 16, 0, 0);
}

// ---------------- fp32 -> bf16 convert, 8 elems/thread ----------------
__global__ __launch_bounds__(256) void cvt_kernel(const float* __restrict__ src,
                                                  unsigned short* __restrict__ dst){
  size_t i = ((size_t)blockIdx.x * 256u + threadIdx.x) * 8u;
  f32x4 a = *(const f32x4*)(src + i);
  f32x4 b = *(const f32x4*)(src + i + 4);
  s16x8 o;
  #pragma unroll
  for (int j = 0; j < 4; ++j){ o[j] = (short)f2bf(a[j]); o[4+j] = (short)f2bf(b[j]); }
  *(s16x8*)(dst + i) = o;
}

// ---------------- GEMM: C[m,n] = sum_k A[m,k]*Bw[n,k] + bias[n] ----------------
// Double-buffered LDS, m97-style T3-minimum loop: stage(t+1) issued BEFORE
// compute(t); ONE barrier per K-step whose vmcnt drain waits on loads issued
// a full compute-phase earlier (staging latency overlapped).
template<int MODE>
__global__ __launch_bounds__(256) void gemm_bt(
    const unsigned short* __restrict__ A, const unsigned short* __restrict__ Bw,
    const float* __restrict__ bias, int M, int N, int K,
    unsigned short* __restrict__ q_ws, unsigned short* __restrict__ k_ws,
    unsigned short* __restrict__ vT_ws, float* __restrict__ out)
{
  __shared__ unsigned short As[2][128*32];
  __shared__ unsigned short Bs[2][128*32];
  const int tid = threadIdx.x;
  const int lane = tid & 63, wid = tid >> 6;
  const int g = lane >> 4, lr = lane & 15;
  const int m0 = blockIdx.y * 128, n0 = blockIdx.x * 128;
  const int wr = wid >> 1, wc = wid & 1;

  f32x4 acc[4][4];
  #pragma unroll
  for (int i = 0; i < 4; ++i)
    #pragma unroll
    for (int j = 0; j < 4; ++j) acc[i][j] = (f32x4){0.f,0.f,0.f,0.f};

  auto stage = [&](int kt, int buf){
    const int k0 = kt << 5;
    #pragma unroll
    for (int j = 0; j < 2; ++j){
      const int c = wid*128 + j*64 + lane;   // 0..511 16B-chunks
      const int row = c >> 2, kc = c & 3;
      gload_lds16((const char*)A  + (((size_t)(m0+row))*K + k0)*2 + kc*16,
                  (char*)&As[buf][0] + (size_t)c*16);
      gload_lds16((const char*)Bw + (((size_t)(n0+row))*K + k0)*2 + kc*16,
                  (char*)&Bs[buf][0] + (size_t)c*16);
    }
  };

  const int nk = K >> 5;
  stage(0, 0);
  __syncthreads();                            // drain prologue stage

  for (int kt = 0; kt < nk; ++kt){
    const int cur = kt & 1;
    if (kt + 1 < nk) stage(kt + 1, cur ^ 1);  // issue next tile BEFORE compute
    s16x8 af[4], bf[4];
    #pragma unroll
    for (int i = 0; i < 4; ++i)
      af[i] = *(const s16x8*)&As[cur][(wr*64 + i*16 + lr)*32 + g*8];
    #pragma unroll
    for (int j = 0; j < 4; ++j)
      bf[j] = *(const s16x8*)&Bs[cur][(wc*64 + j*16 + lr)*32 + g*8];
    #pragma unroll
    for (int i = 0; i < 4; ++i)
      #pragma unroll
      for (int j = 0; j < 4; ++j)
        acc[i][j] = __builtin_amdgcn_mfma_f32_16x16x32_bf16(af[i], bf[j], acc[i][j], 0, 0, 0);
    __syncthreads();                          // drains vmcnt(stage t+1) + swap guard
  }

  #pragma unroll
  for (int i = 0; i < 4; ++i){
    #pragma unroll
    for (int j = 0; j < 4; ++j){
      const int n = n0 + wc*64 + j*16 + lr;
      const float bv = bias[n];
      #pragma unroll
      for (int r = 0; r < 4; ++r){
        const int m = m0 + wr*64 + i*16 + g*4 + r;
        const float val = acc[i][j][r] + bv;
        if (MODE == 0){
          const int which = n >> 10;
          const int cc = n & 1023;
          const int h = cc >> 6, d = cc & 63;
          const int bq = m >> 11, t = m & 2047;
          const int bh = bq*16 + h;
          // q pre-scaled by log2(e)/64 so attention works in exp2 domain
          if (which == 0)      q_ws[((size_t)bh*T_ + t)*D_ + d] = f2bf(val * 0.022542110013890054f);
          else if (which == 1) k_ws[((size_t)bh*T_ + t)*D_ + d] = f2bf(val);
          else                 vT_ws[((size_t)bh*D_ + d)*T_ + t] = f2bf(val);
        } else {
          out[(size_t)m*N + n] = val;
        }
      }
    }
  }
}

// ---------------- flash attention v5: balanced pairs, shared K/V staging ----------------
// Block handles q-tiles A=p and B=31-p: every block = 33 tile-units of work
// (1024 equal blocks = exactly 4/CU, no drain tail). A's key range is a prefix
// of B's -> both share staged K/V AND the K fragments. P aliases Ks[cur] after
// a raw s_barrier (all QK^T K-reads done; vmcnt staging stays in flight).
__global__ __launch_bounds__(256, 4) void attn_kernel(
    const unsigned short* __restrict__ q_ws, const unsigned short* __restrict__ k_ws,
    const unsigned short* __restrict__ vT_ws, unsigned short* __restrict__ y_ws)
{
  __shared__ __align__(16) unsigned short Ks[2][64*64];   // [key][d]  8KB x2 (P aliases Ks[cur])
  __shared__ __align__(16) unsigned short Vs[2][64*64];   // [d][key]  8KB x2

  const int tid = threadIdx.x;
  const int lane = tid & 63, wid = tid >> 6;
  const int g = lane >> 4, lr = lane & 15;
  const int orig = (int)blockIdx.x;
  const int wgid = (orig & 7) * 128 + (orig >> 3);        // XCD-chunk: same-bh blocks colocate on one L2
  const int p  = wgid & 15;
  const int bh = wgid >> 4;
  const int qwA = p*64 + wid*16,  qwB = (31 - p)*64 + wid*16;
  const int qrowA = qwA + lr,     qrowB = qwB + lr;
  const int swz = (lr & 7) << 4;

  const unsigned short* Qb = q_ws  + (size_t)bh*T_*D_;
  const unsigned short* Kb = k_ws  + (size_t)bh*T_*D_;
  const unsigned short* Vb = vT_ws + (size_t)bh*D_*T_;

  auto stage = [&](int t, int buf){
    const int kt0 = t << 6;
    #pragma unroll
    for (int s = 0; s < 2; ++s){
      const int c = s*256 + tid;
      const int r = c >> 3;
      const int scol = ((c & 7) << 4) ^ ((r & 7) << 4);
      gload_lds16((const char*)Kb + ((size_t)(kt0 + r)*D_)*2 + scol,
                  (char*)&Ks[buf][0] + c*16);
      gload_lds16((const char*)Vb + ((size_t)r*T_ + kt0)*2 + scol,
                  (char*)&Vs[buf][0] + c*16);
    }
  };

  const s16x8 bqA0 = *(const s16x8*)&Qb[(size_t)(qwA+lr)*D_ + g*8];
  const s16x8 bqA1 = *(const s16x8*)&Qb[(size_t)(qwA+lr)*D_ + 32 + g*8];
  const s16x8 bqB0 = *(const s16x8*)&Qb[(size_t)(qwB+lr)*D_ + g*8];
  const s16x8 bqB1 = *(const s16x8*)&Qb[(size_t)(qwB+lr)*D_ + 32 + g*8];

  s16x8 ones;
  #pragma unroll
  for (int j = 0; j < 8; ++j) ones[j] = (short)0x3F80;

  f32x4 yA[4], yB[4];
  #pragma unroll
  for (int dt = 0; dt < 4; ++dt){ yA[dt] = (f32x4){0.f,0.f,0.f,0.f}; yB[dt] = (f32x4){0.f,0.f,0.f,0.f}; }
  f32x4 lacA = (f32x4){0.f,0.f,0.f,0.f}, lacB = (f32x4){0.f,0.f,0.f,0.f};
  float mA = -1e30f, mB = -1e30f;

  const int ntA = p + 1, ntB = 32 - p;
  stage(0, 0);
  __syncthreads();

  for (int t = 0; t < ntB; ++t){
    const int cur = t & 1;
    if (t + 1 < ntB) stage(t + 1, cur ^ 1);
    const int kt0 = t << 6;
    const unsigned short* Kt = &Ks[cur][0];
    const unsigned short* Vt = &Vs[cur][0];
    unsigned short* Pw = &Ks[cur][wid*1024];
    const bool actA = (t < ntA);                 // wave-uniform

    // ---- QK^T for B (and A): shared K fragments
    f32x4 sB[4], sA[4];
    #pragma unroll
    for (int kk = 0; kk < 4; ++kk){
      const int row = kk*16 + lr;
      const s16x8 a0 = *(const s16x8*)&Kt[row*64 + (((g*16)      ^ swz) >> 1)];
      const s16x8 a1 = *(const s16x8*)&Kt[row*64 + (((64 + g*16) ^ swz) >> 1)];
      f32x4 acc = (f32x4){0.f,0.f,0.f,0.f};
      acc = __builtin_amdgcn_mfma_f32_16x16x32_bf16(a0, bqB0, acc, 0, 0, 0);
      acc = __builtin_amdgcn_mfma_f32_16x16x32_bf16(a1, bqB1, acc, 0, 0, 0);
      sB[kk] = acc;
      if (actA){
        f32x4 acc2 = (f32x4){0.f,0.f,0.f,0.f};
        acc2 = __builtin_amdgcn_mfma_f32_16x16x32_bf16(a0, bqA0, acc2, 0, 0, 0);
        acc2 = __builtin_amdgcn_mfma_f32_16x16x32_bf16(a1, bqA1, acc2, 0, 0, 0);
        sA[kk] = acc2;
      }
    }

    // ---- softmax B (pre-barrier: registers only)
    if (kt0 + 63 > qwB){
      #pragma unroll
      for (int kk = 0; kk < 4; ++kk)
        #pragma unroll
        for (int r = 0; r < 4; ++r)
          if (kt0 + kk*16 + g*4 + r > qrowB) sB[kk][r] = -1e30f;
    }
    {
      float m01 = fmaxf(fmaxf(sB[0][0], sB[0][1]), fmaxf(sB[0][2], sB[0][3]));
      float m23 = fmaxf(fmaxf(sB[1][0], sB[1][1]), fmaxf(sB[1][2], sB[1][3]));
      float m45 = fmaxf(fmaxf(sB[2][0], sB[2][1]), fmaxf(sB[2][2], sB[2][3]));
      float m67 = fmaxf(fmaxf(sB[3][0], sB[3][1]), fmaxf(sB[3][2], sB[3][3]));
      float mx = fmaxf(fmaxf(m01, m23), fmaxf(m45, m67));
      mx = fmaxf(mx, __shfl_xor(mx, 16, 64));
      mx = fmaxf(mx, __shfl_xor(mx, 32, 64));
      if (!__all(mx <= mB + 8.f)){
        const float mnew = fmaxf(mB, mx);
        const float corr = exp2_asm(mB - mnew);
        mB = mnew;
        lacB[0] *= corr;
        #pragma unroll
        for (int dt = 0; dt < 4; ++dt)
          #pragma unroll
          for (int r = 0; r < 4; ++r) yB[dt][r] *= corr;
      }
    }
    union { unsigned int u[2]; u16x4 v; } pkB[4];
    #pragma unroll
    for (int kk = 0; kk < 4; ++kk){
      const float e0 = exp2_asm(sB[kk][0] - mB);
      const float e1 = exp2_asm(sB[kk][1] - mB);
      const float e2 = exp2_asm(sB[kk][2] - mB);
      const float e3 = exp2_asm(sB[kk][3] - mB);
      pkB[kk].u[0] = cvtpk(e0, e1);
      pkB[kk].u[1] = cvtpk(e2, e3);
    }

    // ---- all waves done reading Ks[cur] (A's QK^T included); vmcnt stays in flight
    asm volatile("s_barrier" ::: "memory");

    // ---- P/PV for B
    #pragma unroll
    for (int kk = 0; kk < 4; ++kk)
      *(u16x4*)&Pw[lr*64 + (((kk*32 + g*8) ^ swz) >> 1)] = pkB[kk].v;
    asm volatile("" ::: "memory");
    {
      const s16x8 p0 = *(const s16x8*)&Pw[lr*64 + (((g*16)      ^ swz) >> 1)];
      const s16x8 p1 = *(const s16x8*)&Pw[lr*64 + (((64 + g*16) ^ swz) >> 1)];
      lacB = __builtin_amdgcn_mfma_f32_16x16x32_bf16(ones, p0, lacB, 0, 0, 0);
      lacB = __builtin_amdgcn_mfma_f32_16x16x32_bf16(ones, p1, lacB, 0, 0, 0);
      #pragma unroll
      for (int dt = 0; dt < 4; ++dt){
        const int vrow = dt*16 + lr;
        const s16x8 v0 = *(const s16x8*)&Vt[vrow*64 + (((g*16)      ^ swz) >> 1)];
        const s16x8 v1 = *(const s16x8*)&Vt[vrow*64 + (((64 + g*16) ^ swz) >> 1)];
        yB[dt] = __builtin_amdgcn_mfma_f32_16x16x32_bf16(v0, p0, yB[dt], 0, 0, 0);
        yB[dt] = __builtin_amdgcn_mfma_f32_16x16x32_bf16(v1, p1, yB[dt], 0, 0, 0);
      }
    }

    // ---- softmax + P/PV for A (P region is per-wave private: in-wave order only)
    if (actA){
      if (kt0 + 63 > qwA){
        #pragma unroll
        for (int kk = 0; kk < 4; ++kk)
          #pragma unroll
          for (int r = 0; r < 4; ++r)
            if (kt0 + kk*16 + g*4 + r > qrowA) sA[kk][r] = -1e30f;
      }
      float m01 = fmaxf(fmaxf(sA[0][0], sA[0][1]), fmaxf(sA[0][2], sA[0][3]));
      float m23 = fmaxf(fmaxf(sA[1][0], sA[1][1]), fmaxf(sA[1][2], sA[1][3]));
      float m45 = fmaxf(fmaxf(sA[2][0], sA[2][1]), fmaxf(sA[2][2], sA[2][3]));
      float m67 = fmaxf(fmaxf(sA[3][0], sA[3][1]), fmaxf(sA[3][2], sA[3][3]));
      float mx = fmaxf(fmaxf(m01, m23), fmaxf(m45, m67));
      mx = fmaxf(mx, __shfl_xor(mx, 16, 64));
      mx = fmaxf(mx, __shfl_xor(mx, 32, 64));
      if (!__all(mx <= mA + 8.f)){
        const float mnew = fmaxf(mA, mx);
        const float corr = exp2_asm(mA - mnew);
        mA = mnew;
        lacA[0] *= corr;
        #pragma unroll
        for (int dt = 0; dt < 4; ++dt)
          #pragma unroll
          for (int r = 0; r < 4; ++r) yA[dt][r] *= corr;
      }
      union { unsigned int u[2]; u16x4 v; } pkA[4];
      #pragma unroll
      for (int kk = 0; kk < 4; ++kk){
        const float e0 = exp2_asm(sA[kk][0] - mA);
        const float e1 = exp2_asm(sA[kk][1] - mA);
        const float e2 = exp2_asm(sA[kk][2] - mA);
        const float e3 = exp2_asm(sA[kk][3] - mA);
        pkA[kk].u[0] = cvtpk(e0, e1);
        pkA[kk].u[1] = cvtpk(e2, e3);
      }
      asm volatile("" ::: "memory");
      #pragma unroll
      for (int kk = 0; kk < 4; ++kk)
        *(u16x4*)&Pw[lr*64 + (((kk*32 + g*8) ^ swz) >> 1)] = pkA[kk].v;
      asm volatile("" ::: "memory");
      const s16x8 p0 = *(const s16x8*)&Pw[lr*64 + (((g*16)      ^ swz) >> 1)];
      const s16x8 p1 = *(const s16x8*)&Pw[lr*64 + (((64 + g*16) ^ swz) >> 1)];
      lacA = __builtin_amdgcn_mfma_f32_16x16x32_bf16(ones, p0, lacA, 0, 0, 0);
      lacA = __builtin_amdgcn_mfma_f32_16x16x32_bf16(ones, p1, lacA, 0, 0, 0);
      #pragma unroll
      for (int dt = 0; dt < 4; ++dt){
        const int vrow = dt*16 + lr;
        const s16x8 v0 = *(const s16x8*)&Vt[vrow*64 + (((g*16)      ^ swz) >> 1)];
        const s16x8 v1 = *(const s16x8*)&Vt[vrow*64 + (((64 + g*16) ^ swz) >> 1)];
        yA[dt] = __builtin_amdgcn_mfma_f32_16x16x32_bf16(v0, p0, yA[dt], 0, 0, 0);
        yA[dt] = __builtin_amdgcn_mfma_f32_16x16x32_bf16(v1, p1, yA[dt], 0, 0, 0);
      }
    }

    __syncthreads();   // drains vmcnt (stage t+1) + protects buffer swap / P region
  }

  const int bq = bh >> 4, h = bh & 15;
  {
    const float inv = 1.f / lacB[0];
    #pragma unroll
    for (int dt = 0; dt < 4; ++dt){
      union { unsigned int u[2]; u16x4 v; } w;
      w.u[0] = cvtpk(yB[dt][0]*inv, yB[dt][1]*inv);
      w.u[1] = cvtpk(yB[dt][2]*inv, yB[dt][3]*inv);
      *(u16x4*)&y_ws[((size_t)(bq*T_ + qwB + lr))*C_ + h*64 + dt*16 + g*4] = w.v;
    }
  }
  {
    const float inv = 1.f / lacA[0];
    #pragma unroll
    for (int dt = 0; dt < 4; ++dt){
      union { unsigned int u[2]; u16x4 v; } w;
      w.u[0] = cvtpk(yA[dt][0]*inv, yA[dt][1]*inv);
      w.u[1] = cvtpk(yA[dt][2]*inv, yA[dt][3]*inv);
      *(u16x4*)&y_ws[((size_t)(bq*T_ + qwA + lr))*C_ + h*64 + dt*16 + g*4] = w.v;
    }
  }
}

extern "C" void kernel_launch(void* const* d_in, const int* in_sizes, int n_in,
                              void* d_out, int out_size, void* d_ws, size_t ws_size,
                              hipStream_t stream) {
  const float* x  = (const float*)d_in[0];
  const float* Wa = (const float*)d_in[1];
  const float* ba = (const float*)d_in[2];
  const float* Wp = (const float*)d_in[3];
  const float* bp = (const float*)d_in[4];
  float* out = (float*)d_out;

  char* ws = (char*)d_ws;
  const size_t MB = 1024u*1024u;
  unsigned short* xb  = (unsigned short*)(ws + 0);       // 16 MiB  [8192][1024] bf16
  unsigned short* wab = (unsigned short*)(ws + 16*MB);   //  6 MiB  [3072][1024]
  unsigned short* wpb = (unsigned short*)(ws + 22*MB);   //  2 MiB  [1024][1024]
  unsigned short* qws = (unsigned short*)(ws + 24*MB);   // 16 MiB  [64][2048][64]
  unsigned short* kws = (unsigned short*)(ws + 40*MB);   // 16 MiB  [64][2048][64]
  unsigned short* vT  = (unsigned short*)(ws + 56*MB);   // 16 MiB  [64][64][2048]
  unsigned short* yws = (unsigned short*)(ws + 72*MB);   // 16 MiB  [8192][1024]

  cvt_kernel<<<4096, 256, 0, stream>>>(x,  xb);
  cvt_kernel<<<1536, 256, 0, stream>>>(Wa, wab);
  cvt_kernel<<< 512, 256, 0, stream>>>(Wp, wpb);

  gemm_bt<0><<<dim3(24, 64), 256, 0, stream>>>(xb, wab, ba, 8192, 3072, 1024,
                                               qws, kws, vT, nullptr);
  attn_kernel<<<dim3(1024), 256, 0, stream>>>(qws, kws, vT, yws);
  gemm_bt<1><<<dim3(8, 64), 256, 0, stream>>>(yws, wpb, bp, 8192, 1024, 1024,
                                              nullptr, nullptr, nullptr, out);
}

// Round 7
// 204.340 us; speedup vs baseline: 2.8794x; 1.0163x over previous
//
#include <hip/hip_runtime.h>

typedef __attribute__((ext_vector_type(8))) short s16x8;
typedef __attribute__((ext_vector_type(4))) float f32x4;
typedef __attribute__((ext_vector_type(4))) unsigned short u16x4;

#define T_  2048
#define C_  1024
#define D_  64

__device__ __forceinline__ unsigned short f2bf(float f){
  union { float fv; unsigned int u; } v; v.fv = f;
  unsigned int r = v.u + 0x7FFFu + ((v.u >> 16) & 1u);
  return (unsigned short)(r >> 16);
}

__device__ __forceinline__ float exp2_asm(float x){
  float r; asm("v_exp_f32 %0, %1" : "=v"(r) : "v"(x)); return r;
}
__device__ __forceinline__ unsigned int cvtpk(float lo, float hi){
  unsigned int r; asm("v_cvt_pk_bf16_f32 %0, %1, %2" : "=v"(r) : "v"(lo), "v"(hi)); return r;
}

__device__ __forceinline__ void gload_lds16(const void* g, void* l){
  __builtin_amdgcn_global_load_lds(
      (const __attribute__((address_space(1))) unsigned int*)g,
      (__attribute__((address_space(3))) unsigned int*)l, 16, 0, 0);
}

// ---------------- fp32 -> bf16 convert, 8 elems/thread ----------------
__global__ __launch_bounds__(256) void cvt_kernel(const float* __restrict__ src,
                                                  unsigned short* __restrict__ dst){
  size_t i = ((size_t)blockIdx.x * 256u + threadIdx.x) * 8u;
  f32x4 a = *(const f32x4*)(src + i);
  f32x4 b = *(const f32x4*)(src + i + 4);
  s16x8 o;
  #pragma unroll
  for (int j = 0; j < 4; ++j){ o[j] = (short)f2bf(a[j]); o[4+j] = (short)f2bf(b[j]); }
  *(s16x8*)(dst + i) = o;
}

// ---------------- GEMM 256x128x64, 512 thr, counted-vmcnt phase loop ----------------
// C[m,n] = sum_k A[m,k]*Bw[n,k] + bias[n].
// T2: LDS rows XOR-swizzled (byte ^= (row&7)<<4), inverse-swizzled global src.
// T4: 2-tile prefetch depth, vmcnt(6) at iter head (vmcnt(0) only on last iter).
// T5: setprio around MFMA clusters. 8 waves = 2M x 4N, wave-tile 128x32.
template<int MODE>
__global__ __launch_bounds__(512, 2) void gemm_bt(
    const unsigned short* __restrict__ A, const unsigned short* __restrict__ Bw,
    const float* __restrict__ bias, int M, int N, int K, int nbx,
    unsigned short* __restrict__ q_ws, unsigned short* __restrict__ k_ws,
    unsigned short* __restrict__ vT_ws, float* __restrict__ out)
{
  __shared__ unsigned short Asm[2][256*64];   // 32 KB x2
  __shared__ unsigned short Bsm[2][128*64];   // 16 KB x2
  const int tid = threadIdx.x;
  const int lane = tid & 63, wid = tid >> 6;
  const int g = lane >> 4, lr = lane & 15;
  const int wm = wid >> 2, wn = wid & 3;
  const int nwg = (int)gridDim.x;
  const int cpx = nwg >> 3;
  const int orig = (int)blockIdx.x;
  const int wgid = (orig & 7) * cpx + (orig >> 3);   // XCD-chunked (nwg % 8 == 0)
  const int bx = wgid % nbx, by = wgid / nbx;
  const int m0 = by * 256, n0 = bx * 128;
  const int swz = (lr & 7) << 4;

  f32x4 acc[8][2];
  #pragma unroll
  for (int i = 0; i < 8; ++i){ acc[i][0] = (f32x4){0.f,0.f,0.f,0.f}; acc[i][1] = (f32x4){0.f,0.f,0.f,0.f}; }

  auto stage = [&](int kt, int buf){
    const int k0 = kt << 6;
    #pragma unroll
    for (int j = 0; j < 4; ++j){
      const int c = j*512 + tid;
      const int row = c >> 3, jc = (c & 7) << 4;
      gload_lds16((const char*)A + ((size_t)(m0+row)*K + k0)*2 + (jc ^ ((row & 7) << 4)),
                  (char*)&Asm[buf][0] + (size_t)c*16);
    }
    #pragma unroll
    for (int j = 0; j < 2; ++j){
      const int c = j*512 + tid;
      const int row = c >> 3, jc = (c & 7) << 4;
      gload_lds16((const char*)Bw + ((size_t)(n0+row)*K + k0)*2 + (jc ^ ((row & 7) << 4)),
                  (char*)&Bsm[buf][0] + (size_t)c*16);
    }
  };

  const int nk = K >> 6;
  stage(0, 0);
  stage(1, 1);                                  // 12 outstanding

  for (int kt = 0; kt < nk; ++kt){
    const int cur = kt & 1;
    if (kt < nk - 1) asm volatile("s_waitcnt vmcnt(6)" ::: "memory");  // tile kt landed
    else             asm volatile("s_waitcnt vmcnt(0)" ::: "memory");
    asm volatile("s_barrier" ::: "memory");

    const char* At = (const char*)&Asm[cur][0];
    const char* Bt = (const char*)&Bsm[cur][0];

    s16x8 bf[2][2];
    #pragma unroll
    for (int ni = 0; ni < 2; ++ni){
      const int row = wn*32 + ni*16 + lr;
      #pragma unroll
      for (int s = 0; s < 2; ++s)
        bf[ni][s] = *(const s16x8*)(Bt + row*128 + ((s*64 + g*16) ^ swz));
    }

    // ---- phase A: M-frags 0..3
    {
      s16x8 af[4][2];
      #pragma unroll
      for (int mi = 0; mi < 4; ++mi){
        const int row = wm*128 + mi*16 + lr;
        #pragma unroll
        for (int s = 0; s < 2; ++s)
          af[mi][s] = *(const s16x8*)(At + row*128 + ((s*64 + g*16) ^ swz));
      }
      __builtin_amdgcn_s_setprio(1);
      #pragma unroll
      for (int mi = 0; mi < 4; ++mi)
        #pragma unroll
        for (int ni = 0; ni < 2; ++ni){
          acc[mi][ni] = __builtin_amdgcn_mfma_f32_16x16x32_bf16(af[mi][0], bf[ni][0], acc[mi][ni], 0, 0, 0);
          acc[mi][ni] = __builtin_amdgcn_mfma_f32_16x16x32_bf16(af[mi][1], bf[ni][1], acc[mi][ni], 0, 0, 0);
        }
      __builtin_amdgcn_s_setprio(0);
    }
    // ---- phase B: M-frags 4..7
    {
      s16x8 af[4][2];
      #pragma unroll
      for (int mi = 0; mi < 4; ++mi){
        const int row = wm*128 + (mi+4)*16 + lr;
        #pragma unroll
        for (int s = 0; s < 2; ++s)
          af[mi][s] = *(const s16x8*)(At + row*128 + ((s*64 + g*16) ^ swz));
      }
      __builtin_amdgcn_s_setprio(1);
      #pragma unroll
      for (int mi = 0; mi < 4; ++mi)
        #pragma unroll
        for (int ni = 0; ni < 2; ++ni){
          acc[mi+4][ni] = __builtin_amdgcn_mfma_f32_16x16x32_bf16(af[mi][0], bf[ni][0], acc[mi+4][ni], 0, 0, 0);
          acc[mi+4][ni] = __builtin_amdgcn_mfma_f32_16x16x32_bf16(af[mi][1], bf[ni][1], acc[mi+4][ni], 0, 0, 0);
        }
      __builtin_amdgcn_s_setprio(0);
    }

    asm volatile("s_barrier" ::: "memory");     // all waves done reading buf[cur]
    if (kt + 2 < nk) stage(kt + 2, cur);        // overwrite buf[cur] for tile kt+2
  }

  #pragma unroll
  for (int mi = 0; mi < 8; ++mi){
    #pragma unroll
    for (int ni = 0; ni < 2; ++ni){
      const int n = n0 + wn*32 + ni*16 + lr;
      const float bv = bias[n];
      #pragma unroll
      for (int r = 0; r < 4; ++r){
        const int m = m0 + wm*128 + mi*16 + g*4 + r;
        const float val = acc[mi][ni][r] + bv;
        if (MODE == 0){
          const int which = n >> 10;
          const int cc = n & 1023;
          const int h = cc >> 6, d = cc & 63;
          const int bq = m >> 11, t = m & 2047;
          const int bh = bq*16 + h;
          // q pre-scaled by log2(e)/64 so attention works in exp2 domain
          if (which == 0)      q_ws[((size_t)bh*T_ + t)*D_ + d] = f2bf(val * 0.022542110013890054f);
          else if (which == 1) k_ws[((size_t)bh*T_ + t)*D_ + d] = f2bf(val);
          else                 vT_ws[((size_t)bh*D_ + d)*T_ + t] = f2bf(val);
        } else {
          out[(size_t)m*N + n] = val;
        }
      }
    }
  }
}

// ---------------- flash attention v5: balanced pairs, shared K/V staging ----------------
__global__ __launch_bounds__(256, 4) void attn_kernel(
    const unsigned short* __restrict__ q_ws, const unsigned short* __restrict__ k_ws,
    const unsigned short* __restrict__ vT_ws, unsigned short* __restrict__ y_ws)
{
  __shared__ __align__(16) unsigned short Ks[2][64*64];   // [key][d]  8KB x2 (P aliases Ks[cur])
  __shared__ __align__(16) unsigned short Vs[2][64*64];   // [d][key]  8KB x2

  const int tid = threadIdx.x;
  const int lane = tid & 63, wid = tid >> 6;
  const int g = lane >> 4, lr = lane & 15;
  const int orig = (int)blockIdx.x;
  const int wgid = (orig & 7) * 128 + (orig >> 3);        // XCD-chunk
  const int p  = wgid & 15;
  const int bh = wgid >> 4;
  const int qwA = p*64 + wid*16,  qwB = (31 - p)*64 + wid*16;
  const int qrowA = qwA + lr,     qrowB = qwB + lr;
  const int swz = (lr & 7) << 4;

  const unsigned short* Qb = q_ws  + (size_t)bh*T_*D_;
  const unsigned short* Kb = k_ws  + (size_t)bh*T_*D_;
  const unsigned short* Vb = vT_ws + (size_t)bh*D_*T_;

  auto stage = [&](int t, int buf){
    const int kt0 = t << 6;
    #pragma unroll
    for (int s = 0; s < 2; ++s){
      const int c = s*256 + tid;
      const int r = c >> 3;
      const int scol = ((c & 7) << 4) ^ ((r & 7) << 4);
      gload_lds16((const char*)Kb + ((size_t)(kt0 + r)*D_)*2 + scol,
                  (char*)&Ks[buf][0] + c*16);
      gload_lds16((const char*)Vb + ((size_t)r*T_ + kt0)*2 + scol,
                  (char*)&Vs[buf][0] + c*16);
    }
  };

  const s16x8 bqA0 = *(const s16x8*)&Qb[(size_t)(qwA+lr)*D_ + g*8];
  const s16x8 bqA1 = *(const s16x8*)&Qb[(size_t)(qwA+lr)*D_ + 32 + g*8];
  const s16x8 bqB0 = *(const s16x8*)&Qb[(size_t)(qwB+lr)*D_ + g*8];
  const s16x8 bqB1 = *(const s16x8*)&Qb[(size_t)(qwB+lr)*D_ + 32 + g*8];

  s16x8 ones;
  #pragma unroll
  for (int j = 0; j < 8; ++j) ones[j] = (short)0x3F80;

  f32x4 yA[4], yB[4];
  #pragma unroll
  for (int dt = 0; dt < 4; ++dt){ yA[dt] = (f32x4){0.f,0.f,0.f,0.f}; yB[dt] = (f32x4){0.f,0.f,0.f,0.f}; }
  f32x4 lacA = (f32x4){0.f,0.f,0.f,0.f}, lacB = (f32x4){0.f,0.f,0.f,0.f};
  float mA = -1e30f, mB = -1e30f;

  const int ntA = p + 1, ntB = 32 - p;
  stage(0, 0);
  __syncthreads();

  for (int t = 0; t < ntB; ++t){
    const int cur = t & 1;
    if (t + 1 < ntB) stage(t + 1, cur ^ 1);
    const int kt0 = t << 6;
    const unsigned short* Kt = &Ks[cur][0];
    const unsigned short* Vt = &Vs[cur][0];
    unsigned short* Pw = &Ks[cur][wid*1024];
    const bool actA = (t < ntA);                 // wave-uniform

    f32x4 sB[4], sA[4];
    #pragma unroll
    for (int kk = 0; kk < 4; ++kk){
      const int row = kk*16 + lr;
      const s16x8 a0 = *(const s16x8*)&Kt[row*64 + (((g*16)      ^ swz) >> 1)];
      const s16x8 a1 = *(const s16x8*)&Kt[row*64 + (((64 + g*16) ^ swz) >> 1)];
      f32x4 acc = (f32x4){0.f,0.f,0.f,0.f};
      acc = __builtin_amdgcn_mfma_f32_16x16x32_bf16(a0, bqB0, acc, 0, 0, 0);
      acc = __builtin_amdgcn_mfma_f32_16x16x32_bf16(a1, bqB1, acc, 0, 0, 0);
      sB[kk] = acc;
      if (actA){
        f32x4 acc2 = (f32x4){0.f,0.f,0.f,0.f};
        acc2 = __builtin_amdgcn_mfma_f32_16x16x32_bf16(a0, bqA0, acc2, 0, 0, 0);
        acc2 = __builtin_amdgcn_mfma_f32_16x16x32_bf16(a1, bqA1, acc2, 0, 0, 0);
        sA[kk] = acc2;
      }
    }

    if (kt0 + 63 > qwB){
      #pragma unroll
      for (int kk = 0; kk < 4; ++kk)
        #pragma unroll
        for (int r = 0; r < 4; ++r)
          if (kt0 + kk*16 + g*4 + r > qrowB) sB[kk][r] = -1e30f;
    }
    {
      float m01 = fmaxf(fmaxf(sB[0][0], sB[0][1]), fmaxf(sB[0][2], sB[0][3]));
      float m23 = fmaxf(fmaxf(sB[1][0], sB[1][1]), fmaxf(sB[1][2], sB[1][3]));
      float m45 = fmaxf(fmaxf(sB[2][0], sB[2][1]), fmaxf(sB[2][2], sB[2][3]));
      float m67 = fmaxf(fmaxf(sB[3][0], sB[3][1]), fmaxf(sB[3][2], sB[3][3]));
      float mx = fmaxf(fmaxf(m01, m23), fmaxf(m45, m67));
      mx = fmaxf(mx, __shfl_xor(mx, 16, 64));
      mx = fmaxf(mx, __shfl_xor(mx, 32, 64));
      if (!__all(mx <= mB + 8.f)){
        const float mnew = fmaxf(mB, mx);
        const float corr = exp2_asm(mB - mnew);
        mB = mnew;
        lacB[0] *= corr;
        #pragma unroll
        for (int dt = 0; dt < 4; ++dt)
          #pragma unroll
          for (int r = 0; r < 4; ++r) yB[dt][r] *= corr;
      }
    }
    union { unsigned int u[2]; u16x4 v; } pkB[4];
    #pragma unroll
    for (int kk = 0; kk < 4; ++kk){
      const float e0 = exp2_asm(sB[kk][0] - mB);
      const float e1 = exp2_asm(sB[kk][1] - mB);
      const float e2 = exp2_asm(sB[kk][2] - mB);
      const float e3 = exp2_asm(sB[kk][3] - mB);
      pkB[kk].u[0] = cvtpk(e0, e1);
      pkB[kk].u[1] = cvtpk(e2, e3);
    }

    asm volatile("s_barrier" ::: "memory");

    #pragma unroll
    for (int kk = 0; kk < 4; ++kk)
      *(u16x4*)&Pw[lr*64 + (((kk*32 + g*8) ^ swz) >> 1)] = pkB[kk].v;
    asm volatile("" ::: "memory");
    {
      const s16x8 p0 = *(const s16x8*)&Pw[lr*64 + (((g*16)      ^ swz) >> 1)];
      const s16x8 p1 = *(const s16x8*)&Pw[lr*64 + (((64 + g*16) ^ swz) >> 1)];
      lacB = __builtin_amdgcn_mfma_f32_16x16x32_bf16(ones, p0, lacB, 0, 0, 0);
      lacB = __builtin_amdgcn_mfma_f32_16x16x32_bf16(ones, p1, lacB, 0, 0, 0);
      #pragma unroll
      for (int dt = 0; dt < 4; ++dt){
        const int vrow = dt*16 + lr;
        const s16x8 v0 = *(const s16x8*)&Vt[vrow*64 + (((g*16)      ^ swz) >> 1)];
        const s16x8 v1 = *(const s16x8*)&Vt[vrow*64 + (((64 + g*16) ^ swz) >> 1)];
        yB[dt] = __builtin_amdgcn_mfma_f32_16x16x32_bf16(v0, p0, yB[dt], 0, 0, 0);
        yB[dt] = __builtin_amdgcn_mfma_f32_16x16x32_bf16(v1, p1, yB[dt], 0, 0, 0);
      }
    }

    if (actA){
      if (kt0 + 63 > qwA){
        #pragma unroll
        for (int kk = 0; kk < 4; ++kk)
          #pragma unroll
          for (int r = 0; r < 4; ++r)
            if (kt0 + kk*16 + g*4 + r > qrowA) sA[kk][r] = -1e30f;
      }
      float m01 = fmaxf(fmaxf(sA[0][0], sA[0][1]), fmaxf(sA[0][2], sA[0][3]));
      float m23 = fmaxf(fmaxf(sA[1][0], sA[1][1]), fmaxf(sA[1][2], sA[1][3]));
      float m45 = fmaxf(fmaxf(sA[2][0], sA[2][1]), fmaxf(sA[2][2], sA[2][3]));
      float m67 = fmaxf(fmaxf(sA[3][0], sA[3][1]), fmaxf(sA[3][2], sA[3][3]));
      float mx = fmaxf(fmaxf(m01, m23), fmaxf(m45, m67));
      mx = fmaxf(mx, __shfl_xor(mx, 16, 64));
      mx = fmaxf(mx, __shfl_xor(mx, 32, 64));
      if (!__all(mx <= mA + 8.f)){
        const float mnew = fmaxf(mA, mx);
        const float corr = exp2_asm(mA - mnew);
        mA = mnew;
        lacA[0] *= corr;
        #pragma unroll
        for (int dt = 0; dt < 4; ++dt)
          #pragma unroll
          for (int r = 0; r < 4; ++r) yA[dt][r] *= corr;
      }
      union { unsigned int u[2]; u16x4 v; } pkA[4];
      #pragma unroll
      for (int kk = 0; kk < 4; ++kk){
        const float e0 = exp2_asm(sA[kk][0] - mA);
        const float e1 = exp2_asm(sA[kk][1] - mA);
        const float e2 = exp2_asm(sA[kk][2] - mA);
        const float e3 = exp2_asm(sA[kk][3] - mA);
        pkA[kk].u[0] = cvtpk(e0, e1);
        pkA[kk].u[1] = cvtpk(e2, e3);
      }
      asm volatile("" ::: "memory");
      #pragma unroll
      for (int kk = 0; kk < 4; ++kk)
        *(u16x4*)&Pw[lr*64 + (((kk*32 + g*8) ^ swz) >> 1)] = pkA[kk].v;
      asm volatile("" ::: "memory");
      const s16x8 p0 = *(const s16x8*)&Pw[lr*64 + (((g*16)      ^ swz) >> 1)];
      const s16x8 p1 = *(const s16x8*)&Pw[lr*64 + (((64 + g*16) ^ swz) >> 1)];
      lacA = __builtin_amdgcn_mfma_f32_16x16x32_bf16(ones, p0, lacA, 0, 0, 0);
      lacA = __builtin_amdgcn_mfma_f32_16x16x32_bf16(ones, p1, lacA, 0, 0, 0);
      #pragma unroll
      for (int dt = 0; dt < 4; ++dt){
        const int vrow = dt*16 + lr;
        const s16x8 v0 = *(const s16x8*)&Vt[vrow*64 + (((g*16)      ^ swz) >> 1)];
        const s16x8 v1 = *(const s16x8*)&Vt[vrow*64 + (((64 + g*16) ^ swz) >> 1)];
        yA[dt] = __builtin_amdgcn_mfma_f32_16x16x32_bf16(v0, p0, yA[dt], 0, 0, 0);
        yA[dt] = __builtin_amdgcn_mfma_f32_16x16x32_bf16(v1, p1, yA[dt], 0, 0, 0);
      }
    }

    __syncthreads();
  }

  const int bq = bh >> 4, h = bh & 15;
  {
    const float inv = 1.f / lacB[0];
    #pragma unroll
    for (int dt = 0; dt < 4; ++dt){
      union { unsigned int u[2]; u16x4 v; } w;
      w.u[0] = cvtpk(yB[dt][0]*inv, yB[dt][1]*inv);
      w.u[1] = cvtpk(yB[dt][2]*inv, yB[dt][3]*inv);
      *(u16x4*)&y_ws[((size_t)(bq*T_ + qwB + lr))*C_ + h*64 + dt*16 + g*4] = w.v;
    }
  }
  {
    const float inv = 1.f / lacA[0];
    #pragma unroll
    for (int dt = 0; dt < 4; ++dt){
      union { unsigned int u[2]; u16x4 v; } w;
      w.u[0] = cvtpk(yA[dt][0]*inv, yA[dt][1]*inv);
      w.u[1] = cvtpk(yA[dt][2]*inv, yA[dt][3]*inv);
      *(u16x4*)&y_ws[((size_t)(bq*T_ + qwA + lr))*C_ + h*64 + dt*16 + g*4] = w.v;
    }
  }
}

extern "C" void kernel_launch(void* const* d_in, const int* in_sizes, int n_in,
                              void* d_out, int out_size, void* d_ws, size_t ws_size,
                              hipStream_t stream) {
  const float* x  = (const float*)d_in[0];
  const float* Wa = (const float*)d_in[1];
  const float* ba = (const float*)d_in[2];
  const float* Wp = (const float*)d_in[3];
  const float* bp = (const float*)d_in[4];
  float* out = (float*)d_out;

  char* ws = (char*)d_ws;
  const size_t MB = 1024u*1024u;
  unsigned short* xb  = (unsigned short*)(ws + 0);       // 16 MiB  [8192][1024] bf16
  unsigned short* wab = (unsigned short*)(ws + 16*MB);   //  6 MiB  [3072][1024]
  unsigned short* wpb = (unsigned short*)(ws + 22*MB);   //  2 MiB  [1024][1024]
  unsigned short* qws = (unsigned short*)(ws + 24*MB);   // 16 MiB  [64][2048][64]
  unsigned short* kws = (unsigned short*)(ws + 40*MB);   // 16 MiB  [64][2048][64]
  unsigned short* vT  = (unsigned short*)(ws + 56*MB);   // 16 MiB  [64][64][2048]
  unsigned short* yws = (unsigned short*)(ws + 72*MB);   // 16 MiB  [8192][1024]

  cvt_kernel<<<4096, 256, 0, stream>>>(x,  xb);
  cvt_kernel<<<1536, 256, 0, stream>>>(Wa, wab);
  cvt_kernel<<< 512, 256, 0, stream>>>(Wp, wpb);

  // QKV: M=8192, N=3072 -> 24x32 = 768 blocks (3 full rounds of 256 CUs)
  gemm_bt<0><<<dim3(768), 512, 0, stream>>>(xb, wab, ba, 8192, 3072, 1024, 24,
                                            qws, kws, vT, nullptr);
  attn_kernel<<<dim3(1024), 256, 0, stream>>>(qws, kws, vT, yws);
  // proj: M=8192, N=1024 -> 8x32 = 256 blocks (1 full round)
  gemm_bt<1><<<dim3(256), 512, 0, stream>>>(yws, wpb, bp, 8192, 1024, 1024, 8,
                                            nullptr, nullptr, nullptr, out);
}